// Round 14
// baseline (168.653 us; speedup 1.0000x reference)
//
#include <hip/hip_runtime.h>
#include <hip/hip_fp16.h>

typedef unsigned int u32;
typedef __half2 h2;

// ---------------------------------------------------------------------------
// helpers
// ---------------------------------------------------------------------------
__device__ __forceinline__ int   f2i(float x){ return __builtin_bit_cast(int, x); }
__device__ __forceinline__ float i2f(int x)  { return __builtin_bit_cast(float, x); }
__device__ __forceinline__ h2  b2h(u32 x){ return __builtin_bit_cast(h2, x); }
__device__ __forceinline__ u32 h2b(h2 x) { return __builtin_bit_cast(u32, x); }
__device__ __forceinline__ u32 rot16(u32 x){ return (x >> 16) | (x << 16); }

template<int PAT>
__device__ __forceinline__ float swzf(float x){
    return i2f(__builtin_amdgcn_ds_swizzle(f2i(x), PAT));
}
template<int PAT>
__device__ __forceinline__ u32 swzu(u32 x){
    return (u32)__builtin_amdgcn_ds_swizzle((int)x, PAT);
}
// f32 xor32 / sum via permlane32_swap (convention-immune)
__device__ __forceinline__ float xor32f(float x){
    unsigned ux = __builtin_bit_cast(unsigned, x);
    auto r = __builtin_amdgcn_permlane32_swap(ux, ux, false, false);
    float a = __builtin_bit_cast(float, (unsigned)r[0]);
    float b = __builtin_bit_cast(float, (unsigned)r[1]);
    return (a + b) - x;
}
__device__ __forceinline__ float sum32(float x){
    unsigned ux = __builtin_bit_cast(unsigned, x);
    auto r = __builtin_amdgcn_permlane32_swap(ux, ux, false, false);
    float a = __builtin_bit_cast(float, (unsigned)r[0]);
    float b = __builtin_bit_cast(float, (unsigned)r[1]);
    return a + b;
}
// h2 pair-sum over lane-bit 5: own + partner (halves move with the dword)
__device__ __forceinline__ u32 sum32h(u32 x){
    auto r = __builtin_amdgcn_permlane32_swap(x, x, false, false);
    return h2b(__hadd2(b2h((u32)r[0]), b2h((u32)r[1])));
}
// f32 lane-xor on bit B (for MLP reduce + readout butterflies)
template<int B>
__device__ __forceinline__ float lx(float x){
    if constexpr      (B == 0) return swzf<0x041F>(x);
    else if constexpr (B == 1) return swzf<0x081F>(x);
    else if constexpr (B == 2) return swzf<0x101F>(x);
    else if constexpr (B == 3) return swzf<0x201F>(x);
    else if constexpr (B == 4) return swzf<0x401F>(x);
    else                       return xor32f(x);
}
// u32 (h2-packed) lane-xor, bits 0..4 via ds_swizzle
template<int B>
__device__ __forceinline__ u32 lxu(u32 x){
    if constexpr      (B == 0) return swzu<0x041F>(x);
    else if constexpr (B == 1) return swzu<0x081F>(x);
    else if constexpr (B == 2) return swzu<0x101F>(x);
    else if constexpr (B == 3) return swzu<0x201F>(x);
    else                       return swzu<0x401F>(x);
}

// ---------------------------------------------------------------------------
// prep: f32 fused matrices (layer 0 / init) + h2-packed coeffs (layers 1..5)
// ws layout: [0..480) f32 U matrices; u32 words [480..880) h2 coefficients
// ---------------------------------------------------------------------------
__global__ void k_prep(const float* __restrict__ qp, float* __restrict__ ws)
{
    int t = threadIdx.x;
    if (t >= 60) return;
    int l = t / 10, q = t % 10;
    float tx = 0.5f * qp[t*3 + 0];
    float ty = 0.5f * qp[t*3 + 1];
    float tz = 0.5f * qp[t*3 + 2];
    float cx = cosf(tx), sx = sinf(tx);
    float cy = cosf(ty), sy = sinf(ty);
    float cz, sz;
    if (l == 5) { cz = 1.0f; sz = 0.0f; }   // final RZ commutes with Z readout
    else        { cz = cosf(tz); sz = sinf(tz); }
    float m00r =  cy*cx, m00i =  sy*sx;
    float m01r = -sy*cx, m01i = -cy*sx;
    float m10r =  sy*cx, m10i = -cy*sx;
    float m11r =  cy*cx, m11i = -sy*sx;
    float U[8];
    U[0] = m00r*cz + m00i*sz;  U[1] = m00i*cz - m00r*sz;
    U[2] = m01r*cz + m01i*sz;  U[3] = m01i*cz - m01r*sz;
    U[4] = m10r*cz - m10i*sz;  U[5] = m10i*cz + m10r*sz;
    U[6] = m11r*cz - m11i*sz;  U[7] = m11i*cz + m11r*sz;
    #pragma unroll
    for (int j = 0; j < 8; j++) ws[t*8 + j] = U[j];

    if (l >= 1) {
        u32* W = reinterpret_cast<u32*>(ws) + 480 + (l-1)*80 + q*8;
        auto pk2 = [](float a, float b){
            return __builtin_bit_cast(u32, __floats2half2_rn(a, b));
        };
        if (q == 9) {
            // intra-pack gate (amp bit3): mixed rows
            W[0] = pk2(U[0],  U[6]);   // Ar  = (u00r,  u11r)
            W[1] = pk2(-U[1], -U[7]);  // Br  = (-u00i, -u11i)
            W[2] = pk2(U[2],  U[4]);   // Cr  = (u01r,  u10r)
            W[3] = pk2(-U[3], -U[5]);  // Dr  = (-u01i, -u10i)
            W[4] = pk2(U[1],  U[7]);   // Ai2 = (u00i,  u11i)
            W[5] = pk2(U[3],  U[5]);   // Ci2 = (u01i,  u10i)
            W[6] = 0; W[7] = 0;
        } else {
            #pragma unroll
            for (int j = 0; j < 8; j++) W[j] = pk2(U[j], U[j]);
        }
    }
}

// ---------------------------------------------------------------------------
// quantum sim: 1 wave = 2 samples (A, B); qubit q<6 -> lane bit q,
// q>=6 -> amp bit q-6.  Per sample: 16 fp16 complex amps, pack p (u32)
// holds (amp p, amp p+8); pr = re, pi = im.
// ---------------------------------------------------------------------------

// composed CNOT chain: lpar whole-reg pair swap, bpermute pack-permutation,
// static half-rotate where f(p) >= 8.  f(p) = (p ^ (p<<1)) & 15.
__device__ __forceinline__ void chainH(u32 (&a)[8], int baddr, bool lpar)
{
    #pragma unroll
    for (int k = 0; k < 4; k++) {
        u32 t0 = a[2*k], t1 = a[2*k+1];
        a[2*k]   = lpar ? t1 : t0;
        a[2*k+1] = lpar ? t0 : t1;
    }
    auto BP = [&](u32 v){ return (u32)__builtin_amdgcn_ds_bpermute(baddr, (int)v); };
    u32 n0 = BP(a[0]);
    u32 n1 = BP(a[3]);
    u32 n2 = BP(a[6]);
    u32 n3 = BP(a[5]);
    u32 n4 = rot16(BP(a[4]));
    u32 n5 = rot16(BP(a[7]));
    u32 n6 = rot16(BP(a[2]));
    u32 n7 = rot16(BP(a[1]));
    a[0]=n0; a[1]=n1; a[2]=n2; a[3]=n3; a[4]=n4; a[5]=n5; a[6]=n6; a[7]=n7;
}

// gate on lane bit B (0..4) for both samples: partner via ds_swizzle
template<int B>
__device__ __forceinline__ void lane_gateH2(u32 (&prA)[8], u32 (&piA)[8],
                                            u32 (&prB)[8], u32 (&piB)[8],
                                            const u32* __restrict__ W, int lane)
{
    u32 w0=W[0], w1=W[1], w2=W[2], w3=W[3], w4=W[4], w5=W[5], w6=W[6], w7=W[7];
    bool hi = (lane >> B) & 1;
    h2 Msr = b2h(hi ? w6 : w0), Msi = b2h(hi ? w7 : w1);
    h2 Mor = b2h(hi ? w4 : w2), Moi = b2h(hi ? w5 : w3);
    h2 nMsi = __hneg2(Msi), nMoi = __hneg2(Moi);
    #pragma unroll
    for (int k = 0; k < 8; k++){
        h2 aA  = b2h(prA[k]), bA = b2h(piA[k]);
        h2 aB  = b2h(prB[k]), bB = b2h(piB[k]);
        h2 oaA = b2h(lxu<B>(prA[k]));
        h2 obA = b2h(lxu<B>(piA[k]));
        h2 oaB = b2h(lxu<B>(prB[k]));
        h2 obB = b2h(lxu<B>(piB[k]));
        h2 nrA = __hfma2(Msr, aA, __hfma2(nMsi, bA, __hfma2(Mor, oaA, __hmul2(nMoi, obA))));
        h2 niA = __hfma2(Msr, bA, __hfma2(Msi, aA, __hfma2(Mor, obA, __hmul2(Moi, oaA))));
        h2 nrB = __hfma2(Msr, aB, __hfma2(nMsi, bB, __hfma2(Mor, oaB, __hmul2(nMoi, obB))));
        h2 niB = __hfma2(Msr, bB, __hfma2(Msi, aB, __hfma2(Mor, obB, __hmul2(Moi, oaB))));
        prA[k] = h2b(nrA); piA[k] = h2b(niA);
        prB[k] = h2b(nrB); piB[k] = h2b(niB);
    }
}

// gate on lane bit 5 for both samples: pair-sum form via permlane32
__device__ __forceinline__ void lane_gateS5H2(u32 (&prA)[8], u32 (&piA)[8],
                                              u32 (&prB)[8], u32 (&piB)[8],
                                              const u32* __restrict__ W, int lane)
{
    u32 w0=W[0], w1=W[1], w2=W[2], w3=W[3], w4=W[4], w5=W[5], w6=W[6], w7=W[7];
    bool hi = (lane >> 5) & 1;
    h2 Msr = b2h(hi ? w6 : w0), Msi = b2h(hi ? w7 : w1);
    h2 Mor = b2h(hi ? w4 : w2), Moi = b2h(hi ? w5 : w3);
    h2 dsr = __hsub2(Msr, Mor), dsi = __hsub2(Msi, Moi);
    h2 ndsi = __hneg2(dsi), nMoi = __hneg2(Moi);
    #pragma unroll
    for (int k = 0; k < 8; k++){
        h2 aA = b2h(prA[k]), bA = b2h(piA[k]);
        h2 aB = b2h(prB[k]), bB = b2h(piB[k]);
        h2 SrA = b2h(sum32h(prA[k]));
        h2 SiA = b2h(sum32h(piA[k]));
        h2 SrB = b2h(sum32h(prB[k]));
        h2 SiB = b2h(sum32h(piB[k]));
        h2 nrA = __hfma2(dsr, aA, __hfma2(ndsi, bA, __hfma2(Mor, SrA, __hmul2(nMoi, SiA))));
        h2 niA = __hfma2(dsr, bA, __hfma2(dsi, aA, __hfma2(Mor, SiA, __hmul2(Moi, SrA))));
        h2 nrB = __hfma2(dsr, aB, __hfma2(ndsi, bB, __hfma2(Mor, SrB, __hmul2(nMoi, SiB))));
        h2 niB = __hfma2(dsr, bB, __hfma2(dsi, aB, __hfma2(Mor, SiB, __hmul2(Moi, SrB))));
        prA[k] = h2b(nrA); piA[k] = h2b(niA);
        prB[k] = h2b(nrB); piB[k] = h2b(niB);
    }
}

// pack-pair gate (qubits 6,7,8 -> pack-index M2 = 1,2,4) for both samples
template<int M2>
__device__ __forceinline__ void reg_gateH2(u32 (&prA)[8], u32 (&piA)[8],
                                           u32 (&prB)[8], u32 (&piB)[8],
                                           const u32* __restrict__ W)
{
    h2 U00r=b2h(W[0]), U00i=b2h(W[1]), U01r=b2h(W[2]), U01i=b2h(W[3]);
    h2 U10r=b2h(W[4]), U10i=b2h(W[5]), U11r=b2h(W[6]), U11i=b2h(W[7]);
    h2 n00i=__hneg2(U00i), n01i=__hneg2(U01i), n10i=__hneg2(U10i), n11i=__hneg2(U11i);
    #pragma unroll
    for (int k = 0; k < 8; k++) if (!(k & M2)) {
        const int k2 = k | M2;
        {
            h2 A0r=b2h(prA[k]), A0i=b2h(piA[k]), A1r=b2h(prA[k2]), A1i=b2h(piA[k2]);
            prA[k]  = h2b(__hfma2(U00r,A0r, __hfma2(n00i,A0i, __hfma2(U01r,A1r, __hmul2(n01i,A1i)))));
            piA[k]  = h2b(__hfma2(U00r,A0i, __hfma2(U00i,A0r, __hfma2(U01r,A1i, __hmul2(U01i,A1r)))));
            prA[k2] = h2b(__hfma2(U10r,A0r, __hfma2(n10i,A0i, __hfma2(U11r,A1r, __hmul2(n11i,A1i)))));
            piA[k2] = h2b(__hfma2(U10r,A0i, __hfma2(U10i,A0r, __hfma2(U11r,A1i, __hmul2(U11i,A1r)))));
        }
        {
            h2 A0r=b2h(prB[k]), A0i=b2h(piB[k]), A1r=b2h(prB[k2]), A1i=b2h(piB[k2]);
            prB[k]  = h2b(__hfma2(U00r,A0r, __hfma2(n00i,A0i, __hfma2(U01r,A1r, __hmul2(n01i,A1i)))));
            piB[k]  = h2b(__hfma2(U00r,A0i, __hfma2(U00i,A0r, __hfma2(U01r,A1i, __hmul2(U01i,A1r)))));
            prB[k2] = h2b(__hfma2(U10r,A0r, __hfma2(n10i,A0i, __hfma2(U11r,A1r, __hmul2(n11i,A1i)))));
            piB[k2] = h2b(__hfma2(U10r,A0i, __hfma2(U10i,A0r, __hfma2(U11r,A1i, __hmul2(U11i,A1r)))));
        }
    }
}

// intra-pack gate (qubit 9 -> amp bit 3 = the two halves) for both samples
__device__ __forceinline__ void q9_gateH2(u32 (&prA)[8], u32 (&piA)[8],
                                          u32 (&prB)[8], u32 (&piB)[8],
                                          const u32* __restrict__ W)
{
    h2 Ar=b2h(W[0]), Br=b2h(W[1]), Cr=b2h(W[2]), Dr=b2h(W[3]);
    h2 Ai2=b2h(W[4]), Ci2=b2h(W[5]);
    #pragma unroll
    for (int k = 0; k < 8; k++){
        h2 aA  = b2h(prA[k]),        bA  = b2h(piA[k]);
        h2 asA = b2h(rot16(prA[k])), bsA = b2h(rot16(piA[k]));
        h2 aB  = b2h(prB[k]),        bB  = b2h(piB[k]);
        h2 asB = b2h(rot16(prB[k])), bsB = b2h(rot16(piB[k]));
        prA[k] = h2b(__hfma2(Ar,  aA, __hfma2(Br, bA, __hfma2(Cr,  asA, __hmul2(Dr, bsA)))));
        piA[k] = h2b(__hfma2(Ai2, aA, __hfma2(Ar, bA, __hfma2(Ci2, asA, __hmul2(Cr, bsA)))));
        prB[k] = h2b(__hfma2(Ar,  aB, __hfma2(Br, bB, __hfma2(Cr,  asB, __hmul2(Dr, bsB)))));
        piB[k] = h2b(__hfma2(Ai2, aB, __hfma2(Ar, bB, __hfma2(Ci2, asB, __hmul2(Cr, bsB)))));
    }
}

// init one sample's packed state from its angles (+layer-0 gates folded)
__device__ __forceinline__ void init_stateH(u32 (&pr)[8], u32 (&pi)[8],
                                            const float (&cv)[10], const float (&sv)[10],
                                            const float* __restrict__ U0, int lane)
{
    float Lr, Li;
    {
        float v0r = U0[0]*cv[0] + U0[2]*sv[0], v0i = U0[1]*cv[0] + U0[3]*sv[0];
        float v1r = U0[4]*cv[0] + U0[6]*sv[0], v1i = U0[5]*cv[0] + U0[7]*sv[0];
        bool b = lane & 1;
        Lr = b ? v1r : v0r;  Li = b ? v1i : v0i;
    }
    #pragma unroll
    for (int q = 1; q < 6; q++) {
        const float* U = U0 + q*8;
        float v0r = U[0]*cv[q] + U[2]*sv[q], v0i = U[1]*cv[q] + U[3]*sv[q];
        float v1r = U[4]*cv[q] + U[6]*sv[q], v1i = U[5]*cv[q] + U[7]*sv[q];
        bool b = (lane >> q) & 1;
        float fr = b ? v1r : v0r, fi = b ? v1i : v0i;
        float nr = Lr*fr - Li*fi;
        float ni = Lr*fi + Li*fr;
        Lr = nr; Li = ni;
    }
    float vr[4][2], vi[4][2];
    #pragma unroll
    for (int q = 6; q < 10; q++) {
        const float* U = U0 + q*8;
        vr[q-6][0] = U[0]*cv[q] + U[2]*sv[q];  vi[q-6][0] = U[1]*cv[q] + U[3]*sv[q];
        vr[q-6][1] = U[4]*cv[q] + U[6]*sv[q];  vi[q-6][1] = U[5]*cv[q] + U[7]*sv[q];
    }
    float t67r[4], t67i[4], t89r[4], t89i[4];
    #pragma unroll
    for (int m = 0; m < 4; m++) {
        int b0 = m & 1, b1i = (m >> 1) & 1;
        t67r[m] = vr[0][b0]*vr[1][b1i] - vi[0][b0]*vi[1][b1i];
        t67i[m] = vr[0][b0]*vi[1][b1i] + vi[0][b0]*vr[1][b1i];
        t89r[m] = vr[2][b0]*vr[3][b1i] - vi[2][b0]*vi[3][b1i];
        t89i[m] = vr[2][b0]*vi[3][b1i] + vi[2][b0]*vr[3][b1i];
    }
    #pragma unroll
    for (int p = 0; p < 8; p++) {
        const int lo = p & 3, h0 = p >> 2, h1 = h0 + 2;
        float prr0 = t67r[lo]*t89r[h0] - t67i[lo]*t89i[h0];
        float pii0 = t67r[lo]*t89i[h0] + t67i[lo]*t89r[h0];
        float re0 = Lr*prr0 - Li*pii0, im0 = Lr*pii0 + Li*prr0;
        float prr1 = t67r[lo]*t89r[h1] - t67i[lo]*t89i[h1];
        float pii1 = t67r[lo]*t89i[h1] + t67i[lo]*t89r[h1];
        float re1 = Lr*prr1 - Li*pii1, im1 = Lr*pii1 + Li*prr1;
        pr[p] = __builtin_bit_cast(u32, __floats2half2_rn(re0, re1));
        pi[p] = __builtin_bit_cast(u32, __floats2half2_rn(im0, im1));
    }
}

template<int B>
__device__ __forceinline__ float st_signed(float v, int lane){
    float t = lx<B>(v);
    return ((lane >> B) & 1) ? (t - v) : (v - t);
}
template<int B>
__device__ __forceinline__ float st_plain(float v){
    if constexpr (B == 5) return sum32(v);
    else return v + lx<B>(v);
}
template<int I>
__device__ __forceinline__ float z_mixed(float S, int lane){
    float v = st_signed<0>(S, lane);
    if constexpr (I >= 1) v = st_signed<1>(v, lane); else v = st_plain<1>(v);
    if constexpr (I >= 2) v = st_signed<2>(v, lane); else v = st_plain<2>(v);
    if constexpr (I >= 3) v = st_signed<3>(v, lane); else v = st_plain<3>(v);
    if constexpr (I >= 4) v = st_signed<4>(v, lane); else v = st_plain<4>(v);
    if constexpr (I >= 5) v = st_signed<5>(v, lane); else v = st_plain<5>(v);
    return v;
}

// readout: |amp|^2 -> f32, reg trees + lane butterflies
__device__ __forceinline__ void readoutH(const u32 (&pr)[8], const u32 (&pi)[8],
                                         int lane, float (&z)[10])
{
    float P[16];
    #pragma unroll
    for (int p = 0; p < 8; p++) {
        h2 a = b2h(pr[p]), b = b2h(pi[p]);
        float arl = __low2float(a),  ail = __low2float(b);
        float arh = __high2float(a), aih = __high2float(b);
        P[p]     = arl*arl + ail*ail;
        P[p + 8] = arh*arh + aih*aih;
    }
    float u[8], d[8];
    #pragma unroll
    for (int k = 0; k < 8; k++) { u[k] = P[2*k] + P[2*k+1]; d[k] = P[2*k] - P[2*k+1]; }
    float S  = ((u[0]+u[1]) + (u[2]+u[3])) + ((u[4]+u[5]) + (u[6]+u[7]));
    float T0 = ((d[0]+d[1]) + (d[2]+d[3])) + ((d[4]+d[5]) + (d[6]+d[7]));
    float e0 = d[0]-d[1], e1 = d[2]-d[3], e2 = d[4]-d[5], e3 = d[6]-d[7];
    float T1 = (e0+e1) + (e2+e3);
    float f0 = e0-e1, f1 = e2-e3;
    float T2 = f0 + f1;
    float T3 = f0 - f1;
    z[0] = z_mixed<0>(S, lane);
    z[1] = z_mixed<1>(S, lane);
    z[2] = z_mixed<2>(S, lane);
    z[3] = z_mixed<3>(S, lane);
    z[4] = z_mixed<4>(S, lane);
    z[5] = z_mixed<5>(S, lane);
    z[6] = z_mixed<5>(T0, lane);
    z[7] = z_mixed<5>(T1, lane);
    z[8] = z_mixed<5>(T2, lane);
    z[9] = z_mixed<5>(T3, lane);
}

__global__ __launch_bounds__(256)
__attribute__((amdgpu_waves_per_eu(6, 8)))
void k_qsim(
        const float* __restrict__ x,
        const float* __restrict__ W1, const float* __restrict__ b1,
        const float* __restrict__ W2, const float* __restrict__ b2,
        const float* __restrict__ ws,
        const float* __restrict__ W3, const float* __restrict__ b3,
        const float* __restrict__ W4, const float* __restrict__ b4,
        float* __restrict__ out)
{
    const int lane = threadIdx.x & 63;
    int wid0 = (blockIdx.x * 256 + threadIdx.x) >> 6;
    const int wid = __builtin_amdgcn_readfirstlane(wid0);   // wave = sample pair

    // ---- front MLP for both samples (half-wave each) -----------------------
    float cA, sA;
    {
        const int j = lane & 31;
        const float* xr  = x + (2*wid + (lane >> 5)) * 64;  // uniform per half
        const float* w1r = W1 + j * 64;
        float a = b1[j];
        #pragma unroll
        for (int k = 0; k < 64; k += 4) {
            float4 xv = *reinterpret_cast<const float4*>(xr + k);
            float4 wv = *reinterpret_cast<const float4*>(w1r + k);
            a = fmaf(wv.x, xv.x, a);
            a = fmaf(wv.y, xv.y, a);
            a = fmaf(wv.z, xv.z, a);
            a = fmaf(wv.w, xv.w, a);
        }
        float h = fmaxf(a, 0.0f);

        float tsel = 0.0f;
        #pragma unroll
        for (int i = 0; i < 10; i++) {
            float t = W2[i*32 + j] * h;
            t = st_plain<4>(t);  t = st_plain<3>(t);  t = st_plain<2>(t);
            t = st_plain<1>(t);  t = st_plain<0>(t);  // sum within 32-lane half
            t += b2[i];
            if (j == i) tsel = t;     // lane i: A angle i; lane 32+i: B angle i
        }
        float ang = tanhf(tsel) * 1.5707963267948966f;   // (tanh*pi)*0.5
        __sincosf(ang, &sA, &cA);
    }

    u32 prA[8], piA[8], prB[8], piB[8];
    {
        float cv[10], sv[10];
        #pragma unroll
        for (int q = 0; q < 10; q++) {
            cv[q] = i2f(__builtin_amdgcn_readlane(f2i(cA), q));
            sv[q] = i2f(__builtin_amdgcn_readlane(f2i(sA), q));
        }
        init_stateH(prA, piA, cv, sv, ws, lane);
        #pragma unroll
        for (int q = 0; q < 10; q++) {
            cv[q] = i2f(__builtin_amdgcn_readlane(f2i(cA), 32 + q));
            sv[q] = i2f(__builtin_amdgcn_readlane(f2i(sA), 32 + q));
        }
        init_stateH(prB, piB, cv, sv, ws, lane);
    }

    const int  baddr = ((lane ^ (lane << 1)) & 63) << 2;
    const bool lpar  = __builtin_popcount(lane & 63) & 1;
    const u32* WH = reinterpret_cast<const u32*>(ws) + 480;

    // ---- layers: chain(l) then gates(l+1), l = 0..4 (last chain folded) ----
    #pragma unroll 1
    for (int l = 0; l < 5; ++l) {
        chainH(prA, baddr, lpar);
        chainH(piA, baddr, lpar);
        chainH(prB, baddr, lpar);
        chainH(piB, baddr, lpar);
        const u32* Ub = WH + l * 80;
        lane_gateH2<0>(prA, piA, prB, piB, Ub +  0, lane);
        lane_gateH2<1>(prA, piA, prB, piB, Ub +  8, lane);
        lane_gateH2<2>(prA, piA, prB, piB, Ub + 16, lane);
        lane_gateH2<3>(prA, piA, prB, piB, Ub + 24, lane);
        lane_gateH2<4>(prA, piA, prB, piB, Ub + 32, lane);
        lane_gateS5H2 (prA, piA, prB, piB, Ub + 40, lane);
        reg_gateH2<1> (prA, piA, prB, piB, Ub + 48);   // qubit 6
        reg_gateH2<2> (prA, piA, prB, piB, Ub + 56);   // qubit 7
        reg_gateH2<4> (prA, piA, prB, piB, Ub + 64);   // qubit 8
        q9_gateH2     (prA, piA, prB, piB, Ub + 72);   // qubit 9
    }

    // ---- readout + tail MLP for both samples -------------------------------
    float zA[10], zB[10];
    readoutH(prA, piA, lane, zA);
    readoutH(prB, piB, lane, zB);

    float a0A = b4[0], a1A = b4[1], a0B = b4[0], a1B = b4[1];
    #pragma unroll
    for (int j2 = 0; j2 < 16; j2++) {
        float aA = b3[j2], aB = b3[j2];
        #pragma unroll
        for (int q = 0; q < 10; q++) {
            float w = W3[j2*10 + q];
            aA = fmaf(w, zA[q], aA);
            aB = fmaf(w, zB[q], aB);
        }
        aA = fmaxf(aA, 0.0f);
        aB = fmaxf(aB, 0.0f);
        float w40 = W4[j2], w41 = W4[16 + j2];
        a0A = fmaf(w40, aA, a0A);
        a1A = fmaf(w41, aA, a1A);
        a0B = fmaf(w40, aB, a0B);
        a1B = fmaf(w41, aB, a1B);
    }
    if (lane == 0) {
        float4 o; o.x = a0A; o.y = a1A; o.z = a0B; o.w = a1B;
        reinterpret_cast<float4*>(out)[wid] = o;
    }
}

extern "C" void kernel_launch(void* const* d_in, const int* in_sizes, int n_in,
                              void* d_out, int out_size, void* d_ws, size_t ws_size,
                              hipStream_t stream)
{
    (void)in_sizes; (void)n_in; (void)out_size; (void)ws_size;
    const float* x  = (const float*)d_in[0];
    const float* W1 = (const float*)d_in[1];
    const float* b1 = (const float*)d_in[2];
    const float* W2 = (const float*)d_in[3];
    const float* b2 = (const float*)d_in[4];
    const float* qp = (const float*)d_in[5];
    const float* W3 = (const float*)d_in[6];
    const float* b3 = (const float*)d_in[7];
    const float* W4 = (const float*)d_in[8];
    const float* b4 = (const float*)d_in[9];
    float* ws  = (float*)d_ws;
    float* out = (float*)d_out;

    k_prep<<<1, 64, 0, stream>>>(qp, ws);
    k_qsim<<<2048, 256, 0, stream>>>(x, W1, b1, W2, b2, ws, W3, b3, W4, b4, out);
}

// Round 15
// 160.196 us; speedup vs baseline: 1.0528x; 1.0528x over previous
//
#include <hip/hip_runtime.h>
#include <hip/hip_fp16.h>

typedef unsigned int u32;
typedef __half2 h2;

// ---------------------------------------------------------------------------
// helpers
// ---------------------------------------------------------------------------
__device__ __forceinline__ int   f2i(float x){ return __builtin_bit_cast(int, x); }
__device__ __forceinline__ float i2f(int x)  { return __builtin_bit_cast(float, x); }
__device__ __forceinline__ h2  b2h(u32 x){ return __builtin_bit_cast(h2, x); }
__device__ __forceinline__ u32 h2b(h2 x) { return __builtin_bit_cast(u32, x); }
__device__ __forceinline__ u32 rot16(u32 x){ return (x >> 16) | (x << 16); }

template<int PAT>
__device__ __forceinline__ float swzf(float x){
    return i2f(__builtin_amdgcn_ds_swizzle(f2i(x), PAT));
}
template<int PAT>
__device__ __forceinline__ u32 swzu(u32 x){
    return (u32)__builtin_amdgcn_ds_swizzle((int)x, PAT);
}
// f32 xor32 / sum via permlane32_swap (convention-immune)
__device__ __forceinline__ float xor32f(float x){
    unsigned ux = __builtin_bit_cast(unsigned, x);
    auto r = __builtin_amdgcn_permlane32_swap(ux, ux, false, false);
    float a = __builtin_bit_cast(float, (unsigned)r[0]);
    float b = __builtin_bit_cast(float, (unsigned)r[1]);
    return (a + b) - x;
}
__device__ __forceinline__ float sum32(float x){
    unsigned ux = __builtin_bit_cast(unsigned, x);
    auto r = __builtin_amdgcn_permlane32_swap(ux, ux, false, false);
    float a = __builtin_bit_cast(float, (unsigned)r[0]);
    float b = __builtin_bit_cast(float, (unsigned)r[1]);
    return a + b;
}
// h2 pair-sum over lane-bit 5: own + partner (halves move with the dword)
__device__ __forceinline__ u32 sum32h(u32 x){
    auto r = __builtin_amdgcn_permlane32_swap(x, x, false, false);
    return h2b(__hadd2(b2h((u32)r[0]), b2h((u32)r[1])));
}
// f32 lane-xor on bit B (for MLP reduce + readout butterflies)
template<int B>
__device__ __forceinline__ float lx(float x){
    if constexpr      (B == 0) return swzf<0x041F>(x);
    else if constexpr (B == 1) return swzf<0x081F>(x);
    else if constexpr (B == 2) return swzf<0x101F>(x);
    else if constexpr (B == 3) return swzf<0x201F>(x);
    else if constexpr (B == 4) return swzf<0x401F>(x);
    else                       return xor32f(x);
}
// u32 (h2-packed) lane-xor, bits 0..4 via ds_swizzle
template<int B>
__device__ __forceinline__ u32 lxu(u32 x){
    if constexpr      (B == 0) return swzu<0x041F>(x);
    else if constexpr (B == 1) return swzu<0x081F>(x);
    else if constexpr (B == 2) return swzu<0x101F>(x);
    else if constexpr (B == 3) return swzu<0x201F>(x);
    else                       return swzu<0x401F>(x);
}

// ---------------------------------------------------------------------------
// prep: f32 fused matrices (layer 0 / init) + h2-packed coeffs (layers 1..5)
// ws layout: [0..480) f32 U matrices; u32 words [480..880) h2 coefficients
// ---------------------------------------------------------------------------
__global__ void k_prep(const float* __restrict__ qp, float* __restrict__ ws)
{
    int t = threadIdx.x;
    if (t >= 60) return;
    int l = t / 10, q = t % 10;
    float tx = 0.5f * qp[t*3 + 0];
    float ty = 0.5f * qp[t*3 + 1];
    float tz = 0.5f * qp[t*3 + 2];
    float cx = cosf(tx), sx = sinf(tx);
    float cy = cosf(ty), sy = sinf(ty);
    float cz, sz;
    if (l == 5) { cz = 1.0f; sz = 0.0f; }   // final RZ commutes with Z readout
    else        { cz = cosf(tz); sz = sinf(tz); }
    float m00r =  cy*cx, m00i =  sy*sx;
    float m01r = -sy*cx, m01i = -cy*sx;
    float m10r =  sy*cx, m10i = -cy*sx;
    float m11r =  cy*cx, m11i = -sy*sx;
    float U[8];
    U[0] = m00r*cz + m00i*sz;  U[1] = m00i*cz - m00r*sz;
    U[2] = m01r*cz + m01i*sz;  U[3] = m01i*cz - m01r*sz;
    U[4] = m10r*cz - m10i*sz;  U[5] = m10i*cz + m10r*sz;
    U[6] = m11r*cz - m11i*sz;  U[7] = m11i*cz + m11r*sz;
    #pragma unroll
    for (int j = 0; j < 8; j++) ws[t*8 + j] = U[j];

    if (l >= 1) {
        u32* W = reinterpret_cast<u32*>(ws) + 480 + (l-1)*80 + q*8;
        auto pk2 = [](float a, float b){
            return __builtin_bit_cast(u32, __floats2half2_rn(a, b));
        };
        if (q == 9) {
            // intra-pack gate (amp bit3): mixed rows
            W[0] = pk2(U[0],  U[6]);   // Ar  = (u00r,  u11r)
            W[1] = pk2(-U[1], -U[7]);  // Br  = (-u00i, -u11i)
            W[2] = pk2(U[2],  U[4]);   // Cr  = (u01r,  u10r)
            W[3] = pk2(-U[3], -U[5]);  // Dr  = (-u01i, -u10i)
            W[4] = pk2(U[1],  U[7]);   // Ai2 = (u00i,  u11i)
            W[5] = pk2(U[3],  U[5]);   // Ci2 = (u01i,  u10i)
            W[6] = 0; W[7] = 0;
        } else {
            #pragma unroll
            for (int j = 0; j < 8; j++) W[j] = pk2(U[j], U[j]);
        }
    }
}

// ---------------------------------------------------------------------------
// quantum sim: 1 wave = 2 samples (A, B); qubit q<6 -> lane bit q,
// q>=6 -> amp bit q-6.  Per sample: 16 fp16 complex amps, pack p (u32)
// holds (amp p, amp p+8); pr = re, pi = im.
// ---------------------------------------------------------------------------

// composed CNOT chain: lpar whole-reg pair swap, bpermute pack-permutation,
// static half-rotate where f(p) >= 8.  f(p) = (p ^ (p<<1)) & 15.
__device__ __forceinline__ void chainH(u32 (&a)[8], int baddr, bool lpar)
{
    #pragma unroll
    for (int k = 0; k < 4; k++) {
        u32 t0 = a[2*k], t1 = a[2*k+1];
        a[2*k]   = lpar ? t1 : t0;
        a[2*k+1] = lpar ? t0 : t1;
    }
    auto BP = [&](u32 v){ return (u32)__builtin_amdgcn_ds_bpermute(baddr, (int)v); };
    u32 n0 = BP(a[0]);
    u32 n1 = BP(a[3]);
    u32 n2 = BP(a[6]);
    u32 n3 = BP(a[5]);
    u32 n4 = rot16(BP(a[4]));
    u32 n5 = rot16(BP(a[7]));
    u32 n6 = rot16(BP(a[2]));
    u32 n7 = rot16(BP(a[1]));
    a[0]=n0; a[1]=n1; a[2]=n2; a[3]=n3; a[4]=n4; a[5]=n5; a[6]=n6; a[7]=n7;
}

// gate on lane bit B (0..4) for both samples: partner via ds_swizzle
template<int B>
__device__ __forceinline__ void lane_gateH2(u32 (&prA)[8], u32 (&piA)[8],
                                            u32 (&prB)[8], u32 (&piB)[8],
                                            const u32* __restrict__ W, int lane)
{
    u32 w0=W[0], w1=W[1], w2=W[2], w3=W[3], w4=W[4], w5=W[5], w6=W[6], w7=W[7];
    bool hi = (lane >> B) & 1;
    h2 Msr = b2h(hi ? w6 : w0), Msi = b2h(hi ? w7 : w1);
    h2 Mor = b2h(hi ? w4 : w2), Moi = b2h(hi ? w5 : w3);
    h2 nMsi = __hneg2(Msi), nMoi = __hneg2(Moi);
    #pragma unroll
    for (int k = 0; k < 8; k++){
        h2 aA  = b2h(prA[k]), bA = b2h(piA[k]);
        h2 aB  = b2h(prB[k]), bB = b2h(piB[k]);
        h2 oaA = b2h(lxu<B>(prA[k]));
        h2 obA = b2h(lxu<B>(piA[k]));
        h2 oaB = b2h(lxu<B>(prB[k]));
        h2 obB = b2h(lxu<B>(piB[k]));
        h2 nrA = __hfma2(Msr, aA, __hfma2(nMsi, bA, __hfma2(Mor, oaA, __hmul2(nMoi, obA))));
        h2 niA = __hfma2(Msr, bA, __hfma2(Msi, aA, __hfma2(Mor, obA, __hmul2(Moi, oaA))));
        h2 nrB = __hfma2(Msr, aB, __hfma2(nMsi, bB, __hfma2(Mor, oaB, __hmul2(nMoi, obB))));
        h2 niB = __hfma2(Msr, bB, __hfma2(Msi, aB, __hfma2(Mor, obB, __hmul2(Moi, oaB))));
        prA[k] = h2b(nrA); piA[k] = h2b(niA);
        prB[k] = h2b(nrB); piB[k] = h2b(niB);
    }
}

// gate on lane bit 5 for both samples: pair-sum form via permlane32
__device__ __forceinline__ void lane_gateS5H2(u32 (&prA)[8], u32 (&piA)[8],
                                              u32 (&prB)[8], u32 (&piB)[8],
                                              const u32* __restrict__ W, int lane)
{
    u32 w0=W[0], w1=W[1], w2=W[2], w3=W[3], w4=W[4], w5=W[5], w6=W[6], w7=W[7];
    bool hi = (lane >> 5) & 1;
    h2 Msr = b2h(hi ? w6 : w0), Msi = b2h(hi ? w7 : w1);
    h2 Mor = b2h(hi ? w4 : w2), Moi = b2h(hi ? w5 : w3);
    h2 dsr = __hsub2(Msr, Mor), dsi = __hsub2(Msi, Moi);
    h2 ndsi = __hneg2(dsi), nMoi = __hneg2(Moi);
    #pragma unroll
    for (int k = 0; k < 8; k++){
        h2 aA = b2h(prA[k]), bA = b2h(piA[k]);
        h2 aB = b2h(prB[k]), bB = b2h(piB[k]);
        h2 SrA = b2h(sum32h(prA[k]));
        h2 SiA = b2h(sum32h(piA[k]));
        h2 SrB = b2h(sum32h(prB[k]));
        h2 SiB = b2h(sum32h(piB[k]));
        h2 nrA = __hfma2(dsr, aA, __hfma2(ndsi, bA, __hfma2(Mor, SrA, __hmul2(nMoi, SiA))));
        h2 niA = __hfma2(dsr, bA, __hfma2(dsi, aA, __hfma2(Mor, SiA, __hmul2(Moi, SrA))));
        h2 nrB = __hfma2(dsr, aB, __hfma2(ndsi, bB, __hfma2(Mor, SrB, __hmul2(nMoi, SiB))));
        h2 niB = __hfma2(dsr, bB, __hfma2(dsi, aB, __hfma2(Mor, SiB, __hmul2(Moi, SrB))));
        prA[k] = h2b(nrA); piA[k] = h2b(niA);
        prB[k] = h2b(nrB); piB[k] = h2b(niB);
    }
}

// pack-pair gate (qubits 6,7,8 -> pack-index M2 = 1,2,4) for both samples
template<int M2>
__device__ __forceinline__ void reg_gateH2(u32 (&prA)[8], u32 (&piA)[8],
                                           u32 (&prB)[8], u32 (&piB)[8],
                                           const u32* __restrict__ W)
{
    h2 U00r=b2h(W[0]), U00i=b2h(W[1]), U01r=b2h(W[2]), U01i=b2h(W[3]);
    h2 U10r=b2h(W[4]), U10i=b2h(W[5]), U11r=b2h(W[6]), U11i=b2h(W[7]);
    h2 n00i=__hneg2(U00i), n01i=__hneg2(U01i), n10i=__hneg2(U10i), n11i=__hneg2(U11i);
    #pragma unroll
    for (int k = 0; k < 8; k++) if (!(k & M2)) {
        const int k2 = k | M2;
        {
            h2 A0r=b2h(prA[k]), A0i=b2h(piA[k]), A1r=b2h(prA[k2]), A1i=b2h(piA[k2]);
            prA[k]  = h2b(__hfma2(U00r,A0r, __hfma2(n00i,A0i, __hfma2(U01r,A1r, __hmul2(n01i,A1i)))));
            piA[k]  = h2b(__hfma2(U00r,A0i, __hfma2(U00i,A0r, __hfma2(U01r,A1i, __hmul2(U01i,A1r)))));
            prA[k2] = h2b(__hfma2(U10r,A0r, __hfma2(n10i,A0i, __hfma2(U11r,A1r, __hmul2(n11i,A1i)))));
            piA[k2] = h2b(__hfma2(U10r,A0i, __hfma2(U10i,A0r, __hfma2(U11r,A1i, __hmul2(U11i,A1r)))));
        }
        {
            h2 A0r=b2h(prB[k]), A0i=b2h(piB[k]), A1r=b2h(prB[k2]), A1i=b2h(piB[k2]);
            prB[k]  = h2b(__hfma2(U00r,A0r, __hfma2(n00i,A0i, __hfma2(U01r,A1r, __hmul2(n01i,A1i)))));
            piB[k]  = h2b(__hfma2(U00r,A0i, __hfma2(U00i,A0r, __hfma2(U01r,A1i, __hmul2(U01i,A1r)))));
            prB[k2] = h2b(__hfma2(U10r,A0r, __hfma2(n10i,A0i, __hfma2(U11r,A1r, __hmul2(n11i,A1i)))));
            piB[k2] = h2b(__hfma2(U10r,A0i, __hfma2(U10i,A0r, __hfma2(U11r,A1i, __hmul2(U11i,A1r)))));
        }
    }
}

// intra-pack gate (qubit 9 -> amp bit 3 = the two halves) for both samples
__device__ __forceinline__ void q9_gateH2(u32 (&prA)[8], u32 (&piA)[8],
                                          u32 (&prB)[8], u32 (&piB)[8],
                                          const u32* __restrict__ W)
{
    h2 Ar=b2h(W[0]), Br=b2h(W[1]), Cr=b2h(W[2]), Dr=b2h(W[3]);
    h2 Ai2=b2h(W[4]), Ci2=b2h(W[5]);
    #pragma unroll
    for (int k = 0; k < 8; k++){
        h2 aA  = b2h(prA[k]),        bA  = b2h(piA[k]);
        h2 asA = b2h(rot16(prA[k])), bsA = b2h(rot16(piA[k]));
        h2 aB  = b2h(prB[k]),        bB  = b2h(piB[k]);
        h2 asB = b2h(rot16(prB[k])), bsB = b2h(rot16(piB[k]));
        prA[k] = h2b(__hfma2(Ar,  aA, __hfma2(Br, bA, __hfma2(Cr,  asA, __hmul2(Dr, bsA)))));
        piA[k] = h2b(__hfma2(Ai2, aA, __hfma2(Ar, bA, __hfma2(Ci2, asA, __hmul2(Cr, bsA)))));
        prB[k] = h2b(__hfma2(Ar,  aB, __hfma2(Br, bB, __hfma2(Cr,  asB, __hmul2(Dr, bsB)))));
        piB[k] = h2b(__hfma2(Ai2, aB, __hfma2(Ar, bB, __hfma2(Ci2, asB, __hmul2(Cr, bsB)))));
    }
}

// init one sample's packed state from its angles (+layer-0 gates folded)
__device__ __forceinline__ void init_stateH(u32 (&pr)[8], u32 (&pi)[8],
                                            const float (&cv)[10], const float (&sv)[10],
                                            const float* __restrict__ U0, int lane)
{
    float Lr, Li;
    {
        float v0r = U0[0]*cv[0] + U0[2]*sv[0], v0i = U0[1]*cv[0] + U0[3]*sv[0];
        float v1r = U0[4]*cv[0] + U0[6]*sv[0], v1i = U0[5]*cv[0] + U0[7]*sv[0];
        bool b = lane & 1;
        Lr = b ? v1r : v0r;  Li = b ? v1i : v0i;
    }
    #pragma unroll
    for (int q = 1; q < 6; q++) {
        const float* U = U0 + q*8;
        float v0r = U[0]*cv[q] + U[2]*sv[q], v0i = U[1]*cv[q] + U[3]*sv[q];
        float v1r = U[4]*cv[q] + U[6]*sv[q], v1i = U[5]*cv[q] + U[7]*sv[q];
        bool b = (lane >> q) & 1;
        float fr = b ? v1r : v0r, fi = b ? v1i : v0i;
        float nr = Lr*fr - Li*fi;
        float ni = Lr*fi + Li*fr;
        Lr = nr; Li = ni;
    }
    float vr[4][2], vi[4][2];
    #pragma unroll
    for (int q = 6; q < 10; q++) {
        const float* U = U0 + q*8;
        vr[q-6][0] = U[0]*cv[q] + U[2]*sv[q];  vi[q-6][0] = U[1]*cv[q] + U[3]*sv[q];
        vr[q-6][1] = U[4]*cv[q] + U[6]*sv[q];  vi[q-6][1] = U[5]*cv[q] + U[7]*sv[q];
    }
    float t67r[4], t67i[4], t89r[4], t89i[4];
    #pragma unroll
    for (int m = 0; m < 4; m++) {
        int b0 = m & 1, b1i = (m >> 1) & 1;
        t67r[m] = vr[0][b0]*vr[1][b1i] - vi[0][b0]*vi[1][b1i];
        t67i[m] = vr[0][b0]*vi[1][b1i] + vi[0][b0]*vr[1][b1i];
        t89r[m] = vr[2][b0]*vr[3][b1i] - vi[2][b0]*vi[3][b1i];
        t89i[m] = vr[2][b0]*vi[3][b1i] + vi[2][b0]*vr[3][b1i];
    }
    #pragma unroll
    for (int p = 0; p < 8; p++) {
        const int lo = p & 3, h0 = p >> 2, h1 = h0 + 2;
        float prr0 = t67r[lo]*t89r[h0] - t67i[lo]*t89i[h0];
        float pii0 = t67r[lo]*t89i[h0] + t67i[lo]*t89r[h0];
        float re0 = Lr*prr0 - Li*pii0, im0 = Lr*pii0 + Li*prr0;
        float prr1 = t67r[lo]*t89r[h1] - t67i[lo]*t89i[h1];
        float pii1 = t67r[lo]*t89i[h1] + t67i[lo]*t89r[h1];
        float re1 = Lr*prr1 - Li*pii1, im1 = Lr*pii1 + Li*prr1;
        pr[p] = __builtin_bit_cast(u32, __floats2half2_rn(re0, re1));
        pi[p] = __builtin_bit_cast(u32, __floats2half2_rn(im0, im1));
    }
}

template<int B>
__device__ __forceinline__ float st_signed(float v, int lane){
    float t = lx<B>(v);
    return ((lane >> B) & 1) ? (t - v) : (v - t);
}
template<int B>
__device__ __forceinline__ float st_plain(float v){
    if constexpr (B == 5) return sum32(v);
    else return v + lx<B>(v);
}
template<int I>
__device__ __forceinline__ float z_mixed(float S, int lane){
    float v = st_signed<0>(S, lane);
    if constexpr (I >= 1) v = st_signed<1>(v, lane); else v = st_plain<1>(v);
    if constexpr (I >= 2) v = st_signed<2>(v, lane); else v = st_plain<2>(v);
    if constexpr (I >= 3) v = st_signed<3>(v, lane); else v = st_plain<3>(v);
    if constexpr (I >= 4) v = st_signed<4>(v, lane); else v = st_plain<4>(v);
    if constexpr (I >= 5) v = st_signed<5>(v, lane); else v = st_plain<5>(v);
    return v;
}

// readout: |amp|^2 -> f32, reg trees + lane butterflies
__device__ __forceinline__ void readoutH(const u32 (&pr)[8], const u32 (&pi)[8],
                                         int lane, float (&z)[10])
{
    float P[16];
    #pragma unroll
    for (int p = 0; p < 8; p++) {
        h2 a = b2h(pr[p]), b = b2h(pi[p]);
        float arl = __low2float(a),  ail = __low2float(b);
        float arh = __high2float(a), aih = __high2float(b);
        P[p]     = arl*arl + ail*ail;
        P[p + 8] = arh*arh + aih*aih;
    }
    float u[8], d[8];
    #pragma unroll
    for (int k = 0; k < 8; k++) { u[k] = P[2*k] + P[2*k+1]; d[k] = P[2*k] - P[2*k+1]; }
    float S  = ((u[0]+u[1]) + (u[2]+u[3])) + ((u[4]+u[5]) + (u[6]+u[7]));
    float T0 = ((d[0]+d[1]) + (d[2]+d[3])) + ((d[4]+d[5]) + (d[6]+d[7]));
    float e0 = d[0]-d[1], e1 = d[2]-d[3], e2 = d[4]-d[5], e3 = d[6]-d[7];
    float T1 = (e0+e1) + (e2+e3);
    float f0 = e0-e1, f1 = e2-e3;
    float T2 = f0 + f1;
    float T3 = f0 - f1;
    z[0] = z_mixed<0>(S, lane);
    z[1] = z_mixed<1>(S, lane);
    z[2] = z_mixed<2>(S, lane);
    z[3] = z_mixed<3>(S, lane);
    z[4] = z_mixed<4>(S, lane);
    z[5] = z_mixed<5>(S, lane);
    z[6] = z_mixed<5>(T0, lane);
    z[7] = z_mixed<5>(T1, lane);
    z[8] = z_mixed<5>(T2, lane);
    z[9] = z_mixed<5>(T3, lane);
}

__global__ __launch_bounds__(256)
__attribute__((amdgpu_waves_per_eu(4, 8)))
void k_qsim(
        const float* __restrict__ x,
        const float* __restrict__ W1, const float* __restrict__ b1,
        const float* __restrict__ W2, const float* __restrict__ b2,
        const float* __restrict__ ws,
        const float* __restrict__ W3, const float* __restrict__ b3,
        const float* __restrict__ W4, const float* __restrict__ b4,
        float* __restrict__ out)
{
    const int lane = threadIdx.x & 63;
    int wid0 = (blockIdx.x * 256 + threadIdx.x) >> 6;
    const int wid = __builtin_amdgcn_readfirstlane(wid0);   // wave = sample pair

    // ---- front MLP for both samples (half-wave each) -----------------------
    float cA, sA;
    {
        const int j = lane & 31;
        const float* xr  = x + (2*wid + (lane >> 5)) * 64;  // uniform per half
        const float* w1r = W1 + j * 64;
        float a = b1[j];
        #pragma unroll
        for (int k = 0; k < 64; k += 4) {
            float4 xv = *reinterpret_cast<const float4*>(xr + k);
            float4 wv = *reinterpret_cast<const float4*>(w1r + k);
            a = fmaf(wv.x, xv.x, a);
            a = fmaf(wv.y, xv.y, a);
            a = fmaf(wv.z, xv.z, a);
            a = fmaf(wv.w, xv.w, a);
        }
        float h = fmaxf(a, 0.0f);

        float tsel = 0.0f;
        #pragma unroll
        for (int i = 0; i < 10; i++) {
            float t = W2[i*32 + j] * h;
            t = st_plain<4>(t);  t = st_plain<3>(t);  t = st_plain<2>(t);
            t = st_plain<1>(t);  t = st_plain<0>(t);  // sum within 32-lane half
            t += b2[i];
            if (j == i) tsel = t;     // lane i: A angle i; lane 32+i: B angle i
        }
        float ang = tanhf(tsel) * 1.5707963267948966f;   // (tanh*pi)*0.5
        __sincosf(ang, &sA, &cA);
    }

    u32 prA[8], piA[8], prB[8], piB[8];
    {
        float cv[10], sv[10];
        #pragma unroll
        for (int q = 0; q < 10; q++) {
            cv[q] = i2f(__builtin_amdgcn_readlane(f2i(cA), q));
            sv[q] = i2f(__builtin_amdgcn_readlane(f2i(sA), q));
        }
        init_stateH(prA, piA, cv, sv, ws, lane);
        #pragma unroll
        for (int q = 0; q < 10; q++) {
            cv[q] = i2f(__builtin_amdgcn_readlane(f2i(cA), 32 + q));
            sv[q] = i2f(__builtin_amdgcn_readlane(f2i(sA), 32 + q));
        }
        init_stateH(prB, piB, cv, sv, ws, lane);
    }

    const int  baddr = ((lane ^ (lane << 1)) & 63) << 2;
    const bool lpar  = __builtin_popcount(lane & 63) & 1;
    const u32* WH = reinterpret_cast<const u32*>(ws) + 480;

    // ---- layers: chain(l) then gates(l+1), l = 0..4 (last chain folded) ----
    #pragma unroll 1
    for (int l = 0; l < 5; ++l) {
        chainH(prA, baddr, lpar);
        chainH(piA, baddr, lpar);
        chainH(prB, baddr, lpar);
        chainH(piB, baddr, lpar);
        const u32* Ub = WH + l * 80;
        lane_gateH2<0>(prA, piA, prB, piB, Ub +  0, lane);
        lane_gateH2<1>(prA, piA, prB, piB, Ub +  8, lane);
        lane_gateH2<2>(prA, piA, prB, piB, Ub + 16, lane);
        lane_gateH2<3>(prA, piA, prB, piB, Ub + 24, lane);
        lane_gateH2<4>(prA, piA, prB, piB, Ub + 32, lane);
        lane_gateS5H2 (prA, piA, prB, piB, Ub + 40, lane);
        reg_gateH2<1> (prA, piA, prB, piB, Ub + 48);   // qubit 6
        reg_gateH2<2> (prA, piA, prB, piB, Ub + 56);   // qubit 7
        reg_gateH2<4> (prA, piA, prB, piB, Ub + 64);   // qubit 8
        q9_gateH2     (prA, piA, prB, piB, Ub + 72);   // qubit 9
    }

    // ---- readout + tail MLP for both samples -------------------------------
    float zA[10], zB[10];
    readoutH(prA, piA, lane, zA);
    readoutH(prB, piB, lane, zB);

    float a0A = b4[0], a1A = b4[1], a0B = b4[0], a1B = b4[1];
    #pragma unroll
    for (int j2 = 0; j2 < 16; j2++) {
        float aA = b3[j2], aB = b3[j2];
        #pragma unroll
        for (int q = 0; q < 10; q++) {
            float w = W3[j2*10 + q];
            aA = fmaf(w, zA[q], aA);
            aB = fmaf(w, zB[q], aB);
        }
        aA = fmaxf(aA, 0.0f);
        aB = fmaxf(aB, 0.0f);
        float w40 = W4[j2], w41 = W4[16 + j2];
        a0A = fmaf(w40, aA, a0A);
        a1A = fmaf(w41, aA, a1A);
        a0B = fmaf(w40, aB, a0B);
        a1B = fmaf(w41, aB, a1B);
    }
    if (lane == 0) {
        float4 o; o.x = a0A; o.y = a1A; o.z = a0B; o.w = a1B;
        reinterpret_cast<float4*>(out)[wid] = o;
    }
}

extern "C" void kernel_launch(void* const* d_in, const int* in_sizes, int n_in,
                              void* d_out, int out_size, void* d_ws, size_t ws_size,
                              hipStream_t stream)
{
    (void)in_sizes; (void)n_in; (void)out_size; (void)ws_size;
    const float* x  = (const float*)d_in[0];
    const float* W1 = (const float*)d_in[1];
    const float* b1 = (const float*)d_in[2];
    const float* W2 = (const float*)d_in[3];
    const float* b2 = (const float*)d_in[4];
    const float* qp = (const float*)d_in[5];
    const float* W3 = (const float*)d_in[6];
    const float* b3 = (const float*)d_in[7];
    const float* W4 = (const float*)d_in[8];
    const float* b4 = (const float*)d_in[9];
    float* ws  = (float*)d_ws;
    float* out = (float*)d_out;

    k_prep<<<1, 64, 0, stream>>>(qp, ws);
    k_qsim<<<2048, 256, 0, stream>>>(x, W1, b1, W2, b2, ws, W3, b3, W4, b4, out);
}

// Round 16
// 153.245 us; speedup vs baseline: 1.1005x; 1.0454x over previous
//
#include <hip/hip_runtime.h>
#include <hip/hip_fp16.h>

typedef unsigned int u32;
typedef __half2 h2;

// ---------------------------------------------------------------------------
// helpers
// ---------------------------------------------------------------------------
__device__ __forceinline__ int   f2i(float x){ return __builtin_bit_cast(int, x); }
__device__ __forceinline__ float i2f(int x)  { return __builtin_bit_cast(float, x); }
__device__ __forceinline__ h2  b2h(u32 x){ return __builtin_bit_cast(h2, x); }
__device__ __forceinline__ u32 h2b(h2 x) { return __builtin_bit_cast(u32, x); }
__device__ __forceinline__ u32 rot16(u32 x){ return (x >> 16) | (x << 16); }

template<int PAT>
__device__ __forceinline__ float swzf(float x){
    return i2f(__builtin_amdgcn_ds_swizzle(f2i(x), PAT));
}
template<int PAT>
__device__ __forceinline__ u32 swzu(u32 x){
    return (u32)__builtin_amdgcn_ds_swizzle((int)x, PAT);
}
// f32 xor32 / sum via permlane32_swap (convention-immune)
__device__ __forceinline__ float xor32f(float x){
    unsigned ux = __builtin_bit_cast(unsigned, x);
    auto r = __builtin_amdgcn_permlane32_swap(ux, ux, false, false);
    float a = __builtin_bit_cast(float, (unsigned)r[0]);
    float b = __builtin_bit_cast(float, (unsigned)r[1]);
    return (a + b) - x;
}
__device__ __forceinline__ float sum32(float x){
    unsigned ux = __builtin_bit_cast(unsigned, x);
    auto r = __builtin_amdgcn_permlane32_swap(ux, ux, false, false);
    float a = __builtin_bit_cast(float, (unsigned)r[0]);
    float b = __builtin_bit_cast(float, (unsigned)r[1]);
    return a + b;
}
// h2 pair-sum over lane-bit 5: own + partner (halves move with the dword)
__device__ __forceinline__ u32 sum32h(u32 x){
    auto r = __builtin_amdgcn_permlane32_swap(x, x, false, false);
    return h2b(__hadd2(b2h((u32)r[0]), b2h((u32)r[1])));
}
// f32 lane-xor on bit B (for MLP reduce + readout butterflies)
template<int B>
__device__ __forceinline__ float lx(float x){
    if constexpr      (B == 0) return swzf<0x041F>(x);
    else if constexpr (B == 1) return swzf<0x081F>(x);
    else if constexpr (B == 2) return swzf<0x101F>(x);
    else if constexpr (B == 3) return swzf<0x201F>(x);
    else if constexpr (B == 4) return swzf<0x401F>(x);
    else                       return xor32f(x);
}
// u32 (h2-packed) lane-xor, bits 0..4 via ds_swizzle
template<int B>
__device__ __forceinline__ u32 lxu(u32 x){
    if constexpr      (B == 0) return swzu<0x041F>(x);
    else if constexpr (B == 1) return swzu<0x081F>(x);
    else if constexpr (B == 2) return swzu<0x101F>(x);
    else if constexpr (B == 3) return swzu<0x201F>(x);
    else                       return swzu<0x401F>(x);
}

// ---------------------------------------------------------------------------
// prep: f32 fused matrices (layer 0 / init) + h2-packed coeffs (layers 1..5)
// ws layout: [0..480) f32 U matrices; u32 words [480..880) h2 coefficients
// ---------------------------------------------------------------------------
__global__ void k_prep(const float* __restrict__ qp, float* __restrict__ ws)
{
    int t = threadIdx.x;
    if (t >= 60) return;
    int l = t / 10, q = t % 10;
    float tx = 0.5f * qp[t*3 + 0];
    float ty = 0.5f * qp[t*3 + 1];
    float tz = 0.5f * qp[t*3 + 2];
    float cx = cosf(tx), sx = sinf(tx);
    float cy = cosf(ty), sy = sinf(ty);
    float cz, sz;
    if (l == 5) { cz = 1.0f; sz = 0.0f; }   // final RZ commutes with Z readout
    else        { cz = cosf(tz); sz = sinf(tz); }
    float m00r =  cy*cx, m00i =  sy*sx;
    float m01r = -sy*cx, m01i = -cy*sx;
    float m10r =  sy*cx, m10i = -cy*sx;
    float m11r =  cy*cx, m11i = -sy*sx;
    float U[8];
    U[0] = m00r*cz + m00i*sz;  U[1] = m00i*cz - m00r*sz;
    U[2] = m01r*cz + m01i*sz;  U[3] = m01i*cz - m01r*sz;
    U[4] = m10r*cz - m10i*sz;  U[5] = m10i*cz + m10r*sz;
    U[6] = m11r*cz - m11i*sz;  U[7] = m11i*cz + m11r*sz;
    #pragma unroll
    for (int j = 0; j < 8; j++) ws[t*8 + j] = U[j];

    if (l >= 1) {
        u32* W = reinterpret_cast<u32*>(ws) + 480 + (l-1)*80 + q*8;
        auto pk2 = [](float a, float b){
            return __builtin_bit_cast(u32, __floats2half2_rn(a, b));
        };
        if (q == 9) {
            // intra-pack gate (amp bit3): mixed rows
            W[0] = pk2(U[0],  U[6]);   // Ar  = (u00r,  u11r)
            W[1] = pk2(-U[1], -U[7]);  // Br  = (-u00i, -u11i)
            W[2] = pk2(U[2],  U[4]);   // Cr  = (u01r,  u10r)
            W[3] = pk2(-U[3], -U[5]);  // Dr  = (-u01i, -u10i)
            W[4] = pk2(U[1],  U[7]);   // Ai2 = (u00i,  u11i)
            W[5] = pk2(U[3],  U[5]);   // Ci2 = (u01i,  u10i)
            W[6] = 0; W[7] = 0;
        } else {
            #pragma unroll
            for (int j = 0; j < 8; j++) W[j] = pk2(U[j], U[j]);
        }
    }
}

// ---------------------------------------------------------------------------
// quantum sim: 1 wave = 2 samples (A, B); qubit q<6 -> lane bit q,
// q>=6 -> amp bit q-6.  Per sample: 16 fp16 complex amps, pack p (u32)
// holds (amp p, amp p+8); pr = re, pi = im.
// ---------------------------------------------------------------------------

// composed CNOT chain: lpar whole-reg pair swap, bpermute pack-permutation,
// static half-rotate where f(p) >= 8.  f(p) = (p ^ (p<<1)) & 15.
__device__ __forceinline__ void chainH(u32 (&a)[8], int baddr, bool lpar)
{
    #pragma unroll
    for (int k = 0; k < 4; k++) {
        u32 t0 = a[2*k], t1 = a[2*k+1];
        a[2*k]   = lpar ? t1 : t0;
        a[2*k+1] = lpar ? t0 : t1;
    }
    auto BP = [&](u32 v){ return (u32)__builtin_amdgcn_ds_bpermute(baddr, (int)v); };
    u32 n0 = BP(a[0]);
    u32 n1 = BP(a[3]);
    u32 n2 = BP(a[6]);
    u32 n3 = BP(a[5]);
    u32 n4 = rot16(BP(a[4]));
    u32 n5 = rot16(BP(a[7]));
    u32 n6 = rot16(BP(a[2]));
    u32 n7 = rot16(BP(a[1]));
    a[0]=n0; a[1]=n1; a[2]=n2; a[3]=n3; a[4]=n4; a[5]=n5; a[6]=n6; a[7]=n7;
}

// gate on lane bit B (0..4) for both samples: partner via ds_swizzle
template<int B>
__device__ __forceinline__ void lane_gateH2(u32 (&prA)[8], u32 (&piA)[8],
                                            u32 (&prB)[8], u32 (&piB)[8],
                                            const u32* __restrict__ W, int lane)
{
    u32 w0=W[0], w1=W[1], w2=W[2], w3=W[3], w4=W[4], w5=W[5], w6=W[6], w7=W[7];
    bool hi = (lane >> B) & 1;
    h2 Msr = b2h(hi ? w6 : w0), Msi = b2h(hi ? w7 : w1);
    h2 Mor = b2h(hi ? w4 : w2), Moi = b2h(hi ? w5 : w3);
    h2 nMsi = __hneg2(Msi), nMoi = __hneg2(Moi);
    #pragma unroll
    for (int k = 0; k < 8; k++){
        h2 aA  = b2h(prA[k]), bA = b2h(piA[k]);
        h2 aB  = b2h(prB[k]), bB = b2h(piB[k]);
        h2 oaA = b2h(lxu<B>(prA[k]));
        h2 obA = b2h(lxu<B>(piA[k]));
        h2 oaB = b2h(lxu<B>(prB[k]));
        h2 obB = b2h(lxu<B>(piB[k]));
        h2 nrA = __hfma2(Msr, aA, __hfma2(nMsi, bA, __hfma2(Mor, oaA, __hmul2(nMoi, obA))));
        h2 niA = __hfma2(Msr, bA, __hfma2(Msi, aA, __hfma2(Mor, obA, __hmul2(Moi, oaA))));
        h2 nrB = __hfma2(Msr, aB, __hfma2(nMsi, bB, __hfma2(Mor, oaB, __hmul2(nMoi, obB))));
        h2 niB = __hfma2(Msr, bB, __hfma2(Msi, aB, __hfma2(Mor, obB, __hmul2(Moi, oaB))));
        prA[k] = h2b(nrA); piA[k] = h2b(niA);
        prB[k] = h2b(nrB); piB[k] = h2b(niB);
    }
}

// gate on lane bit 5 for both samples: pair-sum form via permlane32
__device__ __forceinline__ void lane_gateS5H2(u32 (&prA)[8], u32 (&piA)[8],
                                              u32 (&prB)[8], u32 (&piB)[8],
                                              const u32* __restrict__ W, int lane)
{
    u32 w0=W[0], w1=W[1], w2=W[2], w3=W[3], w4=W[4], w5=W[5], w6=W[6], w7=W[7];
    bool hi = (lane >> 5) & 1;
    h2 Msr = b2h(hi ? w6 : w0), Msi = b2h(hi ? w7 : w1);
    h2 Mor = b2h(hi ? w4 : w2), Moi = b2h(hi ? w5 : w3);
    h2 dsr = __hsub2(Msr, Mor), dsi = __hsub2(Msi, Moi);
    h2 ndsi = __hneg2(dsi), nMoi = __hneg2(Moi);
    #pragma unroll
    for (int k = 0; k < 8; k++){
        h2 aA = b2h(prA[k]), bA = b2h(piA[k]);
        h2 aB = b2h(prB[k]), bB = b2h(piB[k]);
        h2 SrA = b2h(sum32h(prA[k]));
        h2 SiA = b2h(sum32h(piA[k]));
        h2 SrB = b2h(sum32h(prB[k]));
        h2 SiB = b2h(sum32h(piB[k]));
        h2 nrA = __hfma2(dsr, aA, __hfma2(ndsi, bA, __hfma2(Mor, SrA, __hmul2(nMoi, SiA))));
        h2 niA = __hfma2(dsr, bA, __hfma2(dsi, aA, __hfma2(Mor, SiA, __hmul2(Moi, SrA))));
        h2 nrB = __hfma2(dsr, aB, __hfma2(ndsi, bB, __hfma2(Mor, SrB, __hmul2(nMoi, SiB))));
        h2 niB = __hfma2(dsr, bB, __hfma2(dsi, aB, __hfma2(Mor, SiB, __hmul2(Moi, SrB))));
        prA[k] = h2b(nrA); piA[k] = h2b(niA);
        prB[k] = h2b(nrB); piB[k] = h2b(niB);
    }
}

// pack-pair gate (qubits 6,7,8 -> pack-index M2 = 1,2,4) for both samples
template<int M2>
__device__ __forceinline__ void reg_gateH2(u32 (&prA)[8], u32 (&piA)[8],
                                           u32 (&prB)[8], u32 (&piB)[8],
                                           const u32* __restrict__ W)
{
    h2 U00r=b2h(W[0]), U00i=b2h(W[1]), U01r=b2h(W[2]), U01i=b2h(W[3]);
    h2 U10r=b2h(W[4]), U10i=b2h(W[5]), U11r=b2h(W[6]), U11i=b2h(W[7]);
    h2 n00i=__hneg2(U00i), n01i=__hneg2(U01i), n10i=__hneg2(U10i), n11i=__hneg2(U11i);
    #pragma unroll
    for (int k = 0; k < 8; k++) if (!(k & M2)) {
        const int k2 = k | M2;
        {
            h2 A0r=b2h(prA[k]), A0i=b2h(piA[k]), A1r=b2h(prA[k2]), A1i=b2h(piA[k2]);
            prA[k]  = h2b(__hfma2(U00r,A0r, __hfma2(n00i,A0i, __hfma2(U01r,A1r, __hmul2(n01i,A1i)))));
            piA[k]  = h2b(__hfma2(U00r,A0i, __hfma2(U00i,A0r, __hfma2(U01r,A1i, __hmul2(U01i,A1r)))));
            prA[k2] = h2b(__hfma2(U10r,A0r, __hfma2(n10i,A0i, __hfma2(U11r,A1r, __hmul2(n11i,A1i)))));
            piA[k2] = h2b(__hfma2(U10r,A0i, __hfma2(U10i,A0r, __hfma2(U11r,A1i, __hmul2(U11i,A1r)))));
        }
        {
            h2 A0r=b2h(prB[k]), A0i=b2h(piB[k]), A1r=b2h(prB[k2]), A1i=b2h(piB[k2]);
            prB[k]  = h2b(__hfma2(U00r,A0r, __hfma2(n00i,A0i, __hfma2(U01r,A1r, __hmul2(n01i,A1i)))));
            piB[k]  = h2b(__hfma2(U00r,A0i, __hfma2(U00i,A0r, __hfma2(U01r,A1i, __hmul2(U01i,A1r)))));
            prB[k2] = h2b(__hfma2(U10r,A0r, __hfma2(n10i,A0i, __hfma2(U11r,A1r, __hmul2(n11i,A1i)))));
            piB[k2] = h2b(__hfma2(U10r,A0i, __hfma2(U10i,A0r, __hfma2(U11r,A1i, __hmul2(U11i,A1r)))));
        }
    }
}

// intra-pack gate (qubit 9 -> amp bit 3 = the two halves) for both samples
__device__ __forceinline__ void q9_gateH2(u32 (&prA)[8], u32 (&piA)[8],
                                          u32 (&prB)[8], u32 (&piB)[8],
                                          const u32* __restrict__ W)
{
    h2 Ar=b2h(W[0]), Br=b2h(W[1]), Cr=b2h(W[2]), Dr=b2h(W[3]);
    h2 Ai2=b2h(W[4]), Ci2=b2h(W[5]);
    #pragma unroll
    for (int k = 0; k < 8; k++){
        h2 aA  = b2h(prA[k]),        bA  = b2h(piA[k]);
        h2 asA = b2h(rot16(prA[k])), bsA = b2h(rot16(piA[k]));
        h2 aB  = b2h(prB[k]),        bB  = b2h(piB[k]);
        h2 asB = b2h(rot16(prB[k])), bsB = b2h(rot16(piB[k]));
        prA[k] = h2b(__hfma2(Ar,  aA, __hfma2(Br, bA, __hfma2(Cr,  asA, __hmul2(Dr, bsA)))));
        piA[k] = h2b(__hfma2(Ai2, aA, __hfma2(Ar, bA, __hfma2(Ci2, asA, __hmul2(Cr, bsA)))));
        prB[k] = h2b(__hfma2(Ar,  aB, __hfma2(Br, bB, __hfma2(Cr,  asB, __hmul2(Dr, bsB)))));
        piB[k] = h2b(__hfma2(Ai2, aB, __hfma2(Ar, bB, __hfma2(Ci2, asB, __hmul2(Cr, bsB)))));
    }
}

// init one sample's packed state from its angles (+layer-0 gates folded)
__device__ __forceinline__ void init_stateH(u32 (&pr)[8], u32 (&pi)[8],
                                            const float (&cv)[10], const float (&sv)[10],
                                            const float* __restrict__ U0, int lane)
{
    float Lr, Li;
    {
        float v0r = U0[0]*cv[0] + U0[2]*sv[0], v0i = U0[1]*cv[0] + U0[3]*sv[0];
        float v1r = U0[4]*cv[0] + U0[6]*sv[0], v1i = U0[5]*cv[0] + U0[7]*sv[0];
        bool b = lane & 1;
        Lr = b ? v1r : v0r;  Li = b ? v1i : v0i;
    }
    #pragma unroll
    for (int q = 1; q < 6; q++) {
        const float* U = U0 + q*8;
        float v0r = U[0]*cv[q] + U[2]*sv[q], v0i = U[1]*cv[q] + U[3]*sv[q];
        float v1r = U[4]*cv[q] + U[6]*sv[q], v1i = U[5]*cv[q] + U[7]*sv[q];
        bool b = (lane >> q) & 1;
        float fr = b ? v1r : v0r, fi = b ? v1i : v0i;
        float nr = Lr*fr - Li*fi;
        float ni = Lr*fi + Li*fr;
        Lr = nr; Li = ni;
    }
    float vr[4][2], vi[4][2];
    #pragma unroll
    for (int q = 6; q < 10; q++) {
        const float* U = U0 + q*8;
        vr[q-6][0] = U[0]*cv[q] + U[2]*sv[q];  vi[q-6][0] = U[1]*cv[q] + U[3]*sv[q];
        vr[q-6][1] = U[4]*cv[q] + U[6]*sv[q];  vi[q-6][1] = U[5]*cv[q] + U[7]*sv[q];
    }
    float t67r[4], t67i[4], t89r[4], t89i[4];
    #pragma unroll
    for (int m = 0; m < 4; m++) {
        int b0 = m & 1, b1i = (m >> 1) & 1;
        t67r[m] = vr[0][b0]*vr[1][b1i] - vi[0][b0]*vi[1][b1i];
        t67i[m] = vr[0][b0]*vi[1][b1i] + vi[0][b0]*vr[1][b1i];
        t89r[m] = vr[2][b0]*vr[3][b1i] - vi[2][b0]*vi[3][b1i];
        t89i[m] = vr[2][b0]*vi[3][b1i] + vi[2][b0]*vr[3][b1i];
    }
    #pragma unroll
    for (int p = 0; p < 8; p++) {
        const int lo = p & 3, h0 = p >> 2, h1 = h0 + 2;
        float prr0 = t67r[lo]*t89r[h0] - t67i[lo]*t89i[h0];
        float pii0 = t67r[lo]*t89i[h0] + t67i[lo]*t89r[h0];
        float re0 = Lr*prr0 - Li*pii0, im0 = Lr*pii0 + Li*prr0;
        float prr1 = t67r[lo]*t89r[h1] - t67i[lo]*t89i[h1];
        float pii1 = t67r[lo]*t89i[h1] + t67i[lo]*t89r[h1];
        float re1 = Lr*prr1 - Li*pii1, im1 = Lr*pii1 + Li*prr1;
        pr[p] = __builtin_bit_cast(u32, __floats2half2_rn(re0, re1));
        pi[p] = __builtin_bit_cast(u32, __floats2half2_rn(im0, im1));
    }
}

template<int B>
__device__ __forceinline__ float st_signed(float v, int lane){
    float t = lx<B>(v);
    return ((lane >> B) & 1) ? (t - v) : (v - t);
}
template<int B>
__device__ __forceinline__ float st_plain(float v){
    if constexpr (B == 5) return sum32(v);
    else return v + lx<B>(v);
}
// full-signed butterfly (all 6 bits) -> value uniform across lanes
__device__ __forceinline__ float z_full(float v, int lane){
    v = st_signed<0>(v, lane);
    v = st_signed<1>(v, lane);
    v = st_signed<2>(v, lane);
    v = st_signed<3>(v, lane);
    v = st_signed<4>(v, lane);
    v = st_signed<5>(v, lane);
    return v;
}
// Walsh-Hadamard stage: lane m ends with W[m] = sum_l v_l (-1)^popcount(l&m)
template<int B>
__device__ __forceinline__ float wht_stage(float v, int lane){
    float t = lx<B>(v);
    return ((lane >> B) & 1) ? (t - v) : (v + t);
}
__device__ __forceinline__ float wht6(float v, int lane){
    v = wht_stage<0>(v, lane);
    v = wht_stage<1>(v, lane);
    v = wht_stage<2>(v, lane);
    v = wht_stage<3>(v, lane);
    v = wht_stage<4>(v, lane);
    v = wht_stage<5>(v, lane);
    return v;
}
__device__ __forceinline__ float rdlane(float v, int l){
    return i2f(__builtin_amdgcn_readlane(f2i(v), l));
}

// reg-side trees: |amp|^2 -> S (plain) and T[4] (signed on amp bits 0..3)
__device__ __forceinline__ void reduceRegs(const u32 (&pr)[8], const u32 (&pi)[8],
                                           float &S, float (&T)[4])
{
    float P[16];
    #pragma unroll
    for (int p = 0; p < 8; p++) {
        h2 a = b2h(pr[p]), b = b2h(pi[p]);
        float arl = __low2float(a),  ail = __low2float(b);
        float arh = __high2float(a), aih = __high2float(b);
        P[p]     = arl*arl + ail*ail;
        P[p + 8] = arh*arh + aih*aih;
    }
    float u[8], d[8];
    #pragma unroll
    for (int k = 0; k < 8; k++) { u[k] = P[2*k] + P[2*k+1]; d[k] = P[2*k] - P[2*k+1]; }
    S    = ((u[0]+u[1]) + (u[2]+u[3])) + ((u[4]+u[5]) + (u[6]+u[7]));
    T[0] = ((d[0]+d[1]) + (d[2]+d[3])) + ((d[4]+d[5]) + (d[6]+d[7]));
    float e0 = d[0]-d[1], e1 = d[2]-d[3], e2 = d[4]-d[5], e3 = d[6]-d[7];
    T[1] = (e0+e1) + (e2+e3);
    float f0 = e0-e1, f1 = e2-e3;
    T[2] = f0 + f1;
    T[3] = f0 - f1;
}

__global__ __launch_bounds__(256)
__attribute__((amdgpu_waves_per_eu(4, 8)))
void k_qsim(
        const float* __restrict__ x,
        const float* __restrict__ W1, const float* __restrict__ b1,
        const float* __restrict__ W2, const float* __restrict__ b2,
        const float* __restrict__ ws,
        const float* __restrict__ W3, const float* __restrict__ b3,
        const float* __restrict__ W4, const float* __restrict__ b4,
        float* __restrict__ out)
{
    const int lane = threadIdx.x & 63;
    int wid0 = (blockIdx.x * 256 + threadIdx.x) >> 6;
    const int wid = __builtin_amdgcn_readfirstlane(wid0);   // wave = sample pair

    // ---- front MLP for both samples (half-wave each) -----------------------
    float cA, sA;
    {
        const int j = lane & 31;
        const float* xr  = x + (2*wid + (lane >> 5)) * 64;  // uniform per half
        const float* w1r = W1 + j * 64;
        float a = b1[j];
        #pragma unroll
        for (int k = 0; k < 64; k += 4) {
            float4 xv = *reinterpret_cast<const float4*>(xr + k);
            float4 wv = *reinterpret_cast<const float4*>(w1r + k);
            a = fmaf(wv.x, xv.x, a);
            a = fmaf(wv.y, xv.y, a);
            a = fmaf(wv.z, xv.z, a);
            a = fmaf(wv.w, xv.w, a);
        }
        float h = fmaxf(a, 0.0f);

        float tsel = 0.0f;
        #pragma unroll
        for (int i = 0; i < 10; i++) {
            float t = W2[i*32 + j] * h;
            t = st_plain<4>(t);  t = st_plain<3>(t);  t = st_plain<2>(t);
            t = st_plain<1>(t);  t = st_plain<0>(t);  // sum within 32-lane half
            t += b2[i];
            if (j == i) tsel = t;     // lane i: A angle i; lane 32+i: B angle i
        }
        float ang = tanhf(tsel) * 1.5707963267948966f;   // (tanh*pi)*0.5
        __sincosf(ang, &sA, &cA);
    }

    u32 prA[8], piA[8], prB[8], piB[8];
    {
        float cv[10], sv[10];
        #pragma unroll
        for (int q = 0; q < 10; q++) {
            cv[q] = rdlane(cA, q);
            sv[q] = rdlane(sA, q);
        }
        init_stateH(prA, piA, cv, sv, ws, lane);
        #pragma unroll
        for (int q = 0; q < 10; q++) {
            cv[q] = rdlane(cA, 32 + q);
            sv[q] = rdlane(sA, 32 + q);
        }
        init_stateH(prB, piB, cv, sv, ws, lane);
    }

    const int  baddr = ((lane ^ (lane << 1)) & 63) << 2;
    const bool lpar  = __builtin_popcount(lane & 63) & 1;
    const u32* WH = reinterpret_cast<const u32*>(ws) + 480;

    // ---- layers: chain(l) then gates(l+1), l = 0..4 (last chain folded) ----
    #pragma unroll 1
    for (int l = 0; l < 5; ++l) {
        chainH(prA, baddr, lpar);
        chainH(piA, baddr, lpar);
        chainH(prB, baddr, lpar);
        chainH(piB, baddr, lpar);
        const u32* Ub = WH + l * 80;
        lane_gateH2<0>(prA, piA, prB, piB, Ub +  0, lane);
        lane_gateH2<1>(prA, piA, prB, piB, Ub +  8, lane);
        lane_gateH2<2>(prA, piA, prB, piB, Ub + 16, lane);
        lane_gateH2<3>(prA, piA, prB, piB, Ub + 24, lane);
        lane_gateH2<4>(prA, piA, prB, piB, Ub + 32, lane);
        lane_gateS5H2 (prA, piA, prB, piB, Ub + 40, lane);
        reg_gateH2<1> (prA, piA, prB, piB, Ub + 48);   // qubit 6
        reg_gateH2<2> (prA, piA, prB, piB, Ub + 56);   // qubit 7
        reg_gateH2<4> (prA, piA, prB, piB, Ub + 64);   // qubit 8
        q9_gateH2     (prA, piA, prB, piB, Ub + 72);   // qubit 9
    }

    // ---- readout: reg trees + one WHT per sample + 4 full-signed -----------
    float SA, TA[4], SB, TB[4];
    reduceRegs(prA, piA, SA, TA);
    reduceRegs(prB, piB, SB, TB);

    float WA = wht6(SA, lane);
    float WB = wht6(SB, lane);
    // z0..z5 = Walsh coefficients at prefix masks {1,3,7,15,31,63}
    float zA0 = rdlane(WA, 1),  zA1 = rdlane(WA, 3),  zA2 = rdlane(WA, 7);
    float zA3 = rdlane(WA, 15), zA4 = rdlane(WA, 31), zA5 = rdlane(WA, 63);
    float zB0 = rdlane(WB, 1),  zB1 = rdlane(WB, 3),  zB2 = rdlane(WB, 7);
    float zB3 = rdlane(WB, 15), zB4 = rdlane(WB, 31), zB5 = rdlane(WB, 63);
    // z6..z9: full-signed lane butterfly of T (uniform across lanes)
    float zA6 = z_full(TA[0], lane), zA7 = z_full(TA[1], lane);
    float zA8 = z_full(TA[2], lane), zA9 = z_full(TA[3], lane);
    float zB6 = z_full(TB[0], lane), zB7 = z_full(TB[1], lane);
    float zB8 = z_full(TB[2], lane), zB9 = z_full(TB[3], lane);

    // ---- tail MLP parallelized: lanes 0-15 sample A, 16-31 sample B --------
    {
        const bool isB = (lane >> 4) & 1;     // lanes 16-31 (and 48-63 junk)
        float z0 = isB ? zB0 : zA0,  z1 = isB ? zB1 : zA1;
        float z2 = isB ? zB2 : zA2,  z3 = isB ? zB3 : zA3;
        float z4 = isB ? zB4 : zA4,  z5 = isB ? zB5 : zA5;
        float z6 = isB ? zB6 : zA6,  z7 = isB ? zB7 : zA7;
        float z8 = isB ? zB8 : zA8,  z9 = isB ? zB9 : zA9;

        const int j = lane & 15;
        const float* w3r = W3 + j * 10;
        float a = b3[j];
        a = fmaf(w3r[0], z0, a);  a = fmaf(w3r[1], z1, a);
        a = fmaf(w3r[2], z2, a);  a = fmaf(w3r[3], z3, a);
        a = fmaf(w3r[4], z4, a);  a = fmaf(w3r[5], z5, a);
        a = fmaf(w3r[6], z6, a);  a = fmaf(w3r[7], z7, a);
        a = fmaf(w3r[8], z8, a);  a = fmaf(w3r[9], z9, a);
        a = fmaxf(a, 0.0f);
        float p0 = a * W4[j];
        float p1 = a * W4[16 + j];
        // reduce within 16-lane groups (bits 0..3)
        p0 = p0 + lx<0>(p0);  p1 = p1 + lx<0>(p1);
        p0 = p0 + lx<1>(p0);  p1 = p1 + lx<1>(p1);
        p0 = p0 + lx<2>(p0);  p1 = p1 + lx<2>(p1);
        p0 = p0 + lx<3>(p0);  p1 = p1 + lx<3>(p1);
        p0 += b4[0];
        p1 += b4[1];
        if ((lane & 0b101111) == 0) {         // lanes 0 (A) and 16 (B)
            reinterpret_cast<float2*>(out)[2*wid + (lane >> 4)] =
                make_float2(p0, p1);
        }
    }
}

extern "C" void kernel_launch(void* const* d_in, const int* in_sizes, int n_in,
                              void* d_out, int out_size, void* d_ws, size_t ws_size,
                              hipStream_t stream)
{
    (void)in_sizes; (void)n_in; (void)out_size; (void)ws_size;
    const float* x  = (const float*)d_in[0];
    const float* W1 = (const float*)d_in[1];
    const float* b1 = (const float*)d_in[2];
    const float* W2 = (const float*)d_in[3];
    const float* b2 = (const float*)d_in[4];
    const float* qp = (const float*)d_in[5];
    const float* W3 = (const float*)d_in[6];
    const float* b3 = (const float*)d_in[7];
    const float* W4 = (const float*)d_in[8];
    const float* b4 = (const float*)d_in[9];
    float* ws  = (float*)d_ws;
    float* out = (float*)d_out;

    k_prep<<<1, 64, 0, stream>>>(qp, ws);
    k_qsim<<<2048, 256, 0, stream>>>(x, W1, b1, W2, b2, ws, W3, b3, W4, b4, out);
}

// Round 17
// 152.222 us; speedup vs baseline: 1.1079x; 1.0067x over previous
//
#include <hip/hip_runtime.h>
#include <hip/hip_fp16.h>

typedef unsigned int u32;
typedef __half2 h2;

// ---------------------------------------------------------------------------
// helpers
// ---------------------------------------------------------------------------
__device__ __forceinline__ int   f2i(float x){ return __builtin_bit_cast(int, x); }
__device__ __forceinline__ float i2f(int x)  { return __builtin_bit_cast(float, x); }
__device__ __forceinline__ h2  b2h(u32 x){ return __builtin_bit_cast(h2, x); }
__device__ __forceinline__ u32 h2b(h2 x) { return __builtin_bit_cast(u32, x); }
__device__ __forceinline__ u32 rot16(u32 x){ return (x >> 16) | (x << 16); }

template<int PAT>
__device__ __forceinline__ float swzf(float x){
    return i2f(__builtin_amdgcn_ds_swizzle(f2i(x), PAT));
}
template<int PAT>
__device__ __forceinline__ u32 swzu(u32 x){
    return (u32)__builtin_amdgcn_ds_swizzle((int)x, PAT);
}
// f32 xor32 / sum via permlane32_swap (convention-immune)
__device__ __forceinline__ float xor32f(float x){
    unsigned ux = __builtin_bit_cast(unsigned, x);
    auto r = __builtin_amdgcn_permlane32_swap(ux, ux, false, false);
    float a = __builtin_bit_cast(float, (unsigned)r[0]);
    float b = __builtin_bit_cast(float, (unsigned)r[1]);
    return (a + b) - x;
}
__device__ __forceinline__ float sum32(float x){
    unsigned ux = __builtin_bit_cast(unsigned, x);
    auto r = __builtin_amdgcn_permlane32_swap(ux, ux, false, false);
    float a = __builtin_bit_cast(float, (unsigned)r[0]);
    float b = __builtin_bit_cast(float, (unsigned)r[1]);
    return a + b;
}
// h2 pair-sum over lane-bit 5: own + partner (halves move with the dword)
__device__ __forceinline__ u32 sum32h(u32 x){
    auto r = __builtin_amdgcn_permlane32_swap(x, x, false, false);
    return h2b(__hadd2(b2h((u32)r[0]), b2h((u32)r[1])));
}
// f32 lane-xor on bit B (for MLP reduce + readout butterflies)
template<int B>
__device__ __forceinline__ float lx(float x){
    if constexpr      (B == 0) return swzf<0x041F>(x);
    else if constexpr (B == 1) return swzf<0x081F>(x);
    else if constexpr (B == 2) return swzf<0x101F>(x);
    else if constexpr (B == 3) return swzf<0x201F>(x);
    else if constexpr (B == 4) return swzf<0x401F>(x);
    else                       return xor32f(x);
}
// u32 (h2-packed) lane-xor, bits 0..4 via ds_swizzle
template<int B>
__device__ __forceinline__ u32 lxu(u32 x){
    if constexpr      (B == 0) return swzu<0x041F>(x);
    else if constexpr (B == 1) return swzu<0x081F>(x);
    else if constexpr (B == 2) return swzu<0x101F>(x);
    else if constexpr (B == 3) return swzu<0x201F>(x);
    else                       return swzu<0x401F>(x);
}

// ---------------------------------------------------------------------------
// prep: f32 fused matrices (layer 0 / init) + h2-packed coeffs (layers 1..5)
// ws layout: [0..480) f32 U matrices; u32 words [480..880) h2 coefficients
// ---------------------------------------------------------------------------
__global__ void k_prep(const float* __restrict__ qp, float* __restrict__ ws)
{
    int t = threadIdx.x;
    if (t >= 60) return;
    int l = t / 10, q = t % 10;
    float tx = 0.5f * qp[t*3 + 0];
    float ty = 0.5f * qp[t*3 + 1];
    float tz = 0.5f * qp[t*3 + 2];
    float cx = cosf(tx), sx = sinf(tx);
    float cy = cosf(ty), sy = sinf(ty);
    float cz, sz;
    if (l == 5) { cz = 1.0f; sz = 0.0f; }   // final RZ commutes with Z readout
    else        { cz = cosf(tz); sz = sinf(tz); }
    float m00r =  cy*cx, m00i =  sy*sx;
    float m01r = -sy*cx, m01i = -cy*sx;
    float m10r =  sy*cx, m10i = -cy*sx;
    float m11r =  cy*cx, m11i = -sy*sx;
    float U[8];
    U[0] = m00r*cz + m00i*sz;  U[1] = m00i*cz - m00r*sz;
    U[2] = m01r*cz + m01i*sz;  U[3] = m01i*cz - m01r*sz;
    U[4] = m10r*cz - m10i*sz;  U[5] = m10i*cz + m10r*sz;
    U[6] = m11r*cz - m11i*sz;  U[7] = m11i*cz + m11r*sz;
    #pragma unroll
    for (int j = 0; j < 8; j++) ws[t*8 + j] = U[j];

    if (l >= 1) {
        u32* W = reinterpret_cast<u32*>(ws) + 480 + (l-1)*80 + q*8;
        auto pk2 = [](float a, float b){
            return __builtin_bit_cast(u32, __floats2half2_rn(a, b));
        };
        if (q == 9) {
            // intra-pack gate (amp bit3): mixed rows
            W[0] = pk2(U[0],  U[6]);   // Ar  = (u00r,  u11r)
            W[1] = pk2(-U[1], -U[7]);  // Br  = (-u00i, -u11i)
            W[2] = pk2(U[2],  U[4]);   // Cr  = (u01r,  u10r)
            W[3] = pk2(-U[3], -U[5]);  // Dr  = (-u01i, -u10i)
            W[4] = pk2(U[1],  U[7]);   // Ai2 = (u00i,  u11i)
            W[5] = pk2(U[3],  U[5]);   // Ci2 = (u01i,  u10i)
            W[6] = 0; W[7] = 0;
        } else {
            #pragma unroll
            for (int j = 0; j < 8; j++) W[j] = pk2(U[j], U[j]);
        }
    }
}

// ---------------------------------------------------------------------------
// quantum sim: 1 wave = 2 samples (A, B); qubit q<6 -> lane bit q,
// q>=6 -> amp bit q-6.  Per sample: 16 fp16 complex amps, pack p (u32)
// holds (amp p, amp p+8); pr = re, pi = im.
// Within-layer gates commute: A and B use PHASE-COMPLEMENTARY orders so A's
// VALU-only reg gates overlap B's DS-heavy chain/lane gates and vice versa.
// ---------------------------------------------------------------------------

// composed CNOT chain: lpar whole-reg pair swap, bpermute pack-permutation,
// static half-rotate where f(p) >= 8.  f(p) = (p ^ (p<<1)) & 15.
__device__ __forceinline__ void chainH(u32 (&a)[8], int baddr, bool lpar)
{
    #pragma unroll
    for (int k = 0; k < 4; k++) {
        u32 t0 = a[2*k], t1 = a[2*k+1];
        a[2*k]   = lpar ? t1 : t0;
        a[2*k+1] = lpar ? t0 : t1;
    }
    auto BP = [&](u32 v){ return (u32)__builtin_amdgcn_ds_bpermute(baddr, (int)v); };
    u32 n0 = BP(a[0]);
    u32 n1 = BP(a[3]);
    u32 n2 = BP(a[6]);
    u32 n3 = BP(a[5]);
    u32 n4 = rot16(BP(a[4]));
    u32 n5 = rot16(BP(a[7]));
    u32 n6 = rot16(BP(a[2]));
    u32 n7 = rot16(BP(a[1]));
    a[0]=n0; a[1]=n1; a[2]=n2; a[3]=n3; a[4]=n4; a[5]=n5; a[6]=n6; a[7]=n7;
}

// gate on lane bit B (0..4), single sample: partner via ds_swizzle
template<int B>
__device__ __forceinline__ void lane_gateH1(u32 (&pr)[8], u32 (&pi)[8],
                                            const u32* __restrict__ W, int lane)
{
    u32 w0=W[0], w1=W[1], w2=W[2], w3=W[3], w4=W[4], w5=W[5], w6=W[6], w7=W[7];
    bool hi = (lane >> B) & 1;
    h2 Msr = b2h(hi ? w6 : w0), Msi = b2h(hi ? w7 : w1);
    h2 Mor = b2h(hi ? w4 : w2), Moi = b2h(hi ? w5 : w3);
    h2 nMsi = __hneg2(Msi), nMoi = __hneg2(Moi);
    #pragma unroll
    for (int k = 0; k < 8; k++){
        h2 a  = b2h(pr[k]), b = b2h(pi[k]);
        h2 oa = b2h(lxu<B>(pr[k]));
        h2 ob = b2h(lxu<B>(pi[k]));
        h2 nr = __hfma2(Msr, a, __hfma2(nMsi, b, __hfma2(Mor, oa, __hmul2(nMoi, ob))));
        h2 ni = __hfma2(Msr, b, __hfma2(Msi, a, __hfma2(Mor, ob, __hmul2(Moi, oa))));
        pr[k] = h2b(nr); pi[k] = h2b(ni);
    }
}

// gate on lane bit 5, single sample: pair-sum form via permlane32 (VALU)
__device__ __forceinline__ void lane_gateS5H1(u32 (&pr)[8], u32 (&pi)[8],
                                              const u32* __restrict__ W, int lane)
{
    u32 w0=W[0], w1=W[1], w2=W[2], w3=W[3], w4=W[4], w5=W[5], w6=W[6], w7=W[7];
    bool hi = (lane >> 5) & 1;
    h2 Msr = b2h(hi ? w6 : w0), Msi = b2h(hi ? w7 : w1);
    h2 Mor = b2h(hi ? w4 : w2), Moi = b2h(hi ? w5 : w3);
    h2 dsr = __hsub2(Msr, Mor), dsi = __hsub2(Msi, Moi);
    h2 ndsi = __hneg2(dsi), nMoi = __hneg2(Moi);
    #pragma unroll
    for (int k = 0; k < 8; k++){
        h2 a = b2h(pr[k]), b = b2h(pi[k]);
        h2 Sr = b2h(sum32h(pr[k]));
        h2 Si = b2h(sum32h(pi[k]));
        h2 nr = __hfma2(dsr, a, __hfma2(ndsi, b, __hfma2(Mor, Sr, __hmul2(nMoi, Si))));
        h2 ni = __hfma2(dsr, b, __hfma2(dsi, a, __hfma2(Mor, Si, __hmul2(Moi, Sr))));
        pr[k] = h2b(nr); pi[k] = h2b(ni);
    }
}

// pack-pair gate (qubits 6,7,8 -> pack-index M2 = 1,2,4), single sample (VALU)
template<int M2>
__device__ __forceinline__ void reg_gateH1(u32 (&pr)[8], u32 (&pi)[8],
                                           const u32* __restrict__ W)
{
    h2 U00r=b2h(W[0]), U00i=b2h(W[1]), U01r=b2h(W[2]), U01i=b2h(W[3]);
    h2 U10r=b2h(W[4]), U10i=b2h(W[5]), U11r=b2h(W[6]), U11i=b2h(W[7]);
    h2 n00i=__hneg2(U00i), n01i=__hneg2(U01i), n10i=__hneg2(U10i), n11i=__hneg2(U11i);
    #pragma unroll
    for (int k = 0; k < 8; k++) if (!(k & M2)) {
        const int k2 = k | M2;
        h2 A0r=b2h(pr[k]), A0i=b2h(pi[k]), A1r=b2h(pr[k2]), A1i=b2h(pi[k2]);
        pr[k]  = h2b(__hfma2(U00r,A0r, __hfma2(n00i,A0i, __hfma2(U01r,A1r, __hmul2(n01i,A1i)))));
        pi[k]  = h2b(__hfma2(U00r,A0i, __hfma2(U00i,A0r, __hfma2(U01r,A1i, __hmul2(U01i,A1r)))));
        pr[k2] = h2b(__hfma2(U10r,A0r, __hfma2(n10i,A0i, __hfma2(U11r,A1r, __hmul2(n11i,A1i)))));
        pi[k2] = h2b(__hfma2(U10r,A0i, __hfma2(U10i,A0r, __hfma2(U11r,A1i, __hmul2(U11i,A1r)))));
    }
}

// intra-pack gate (qubit 9 -> amp bit 3), single sample (VALU)
__device__ __forceinline__ void q9_gateH1(u32 (&pr)[8], u32 (&pi)[8],
                                          const u32* __restrict__ W)
{
    h2 Ar=b2h(W[0]), Br=b2h(W[1]), Cr=b2h(W[2]), Dr=b2h(W[3]);
    h2 Ai2=b2h(W[4]), Ci2=b2h(W[5]);
    #pragma unroll
    for (int k = 0; k < 8; k++){
        h2 a  = b2h(pr[k]),        b  = b2h(pi[k]);
        h2 as = b2h(rot16(pr[k])), bs = b2h(rot16(pi[k]));
        h2 nr = __hfma2(Ar,  a, __hfma2(Br, b, __hfma2(Cr,  as, __hmul2(Dr, bs))));
        h2 ni = __hfma2(Ai2, a, __hfma2(Ar, b, __hfma2(Ci2, as, __hmul2(Cr, bs))));
        pr[k] = h2b(nr); pi[k] = h2b(ni);
    }
}

// init one sample's packed state from its angles (+layer-0 gates folded)
__device__ __forceinline__ void init_stateH(u32 (&pr)[8], u32 (&pi)[8],
                                            const float (&cv)[10], const float (&sv)[10],
                                            const float* __restrict__ U0, int lane)
{
    float Lr, Li;
    {
        float v0r = U0[0]*cv[0] + U0[2]*sv[0], v0i = U0[1]*cv[0] + U0[3]*sv[0];
        float v1r = U0[4]*cv[0] + U0[6]*sv[0], v1i = U0[5]*cv[0] + U0[7]*sv[0];
        bool b = lane & 1;
        Lr = b ? v1r : v0r;  Li = b ? v1i : v0i;
    }
    #pragma unroll
    for (int q = 1; q < 6; q++) {
        const float* U = U0 + q*8;
        float v0r = U[0]*cv[q] + U[2]*sv[q], v0i = U[1]*cv[q] + U[3]*sv[q];
        float v1r = U[4]*cv[q] + U[6]*sv[q], v1i = U[5]*cv[q] + U[7]*sv[q];
        bool b = (lane >> q) & 1;
        float fr = b ? v1r : v0r, fi = b ? v1i : v0i;
        float nr = Lr*fr - Li*fi;
        float ni = Lr*fi + Li*fr;
        Lr = nr; Li = ni;
    }
    float vr[4][2], vi[4][2];
    #pragma unroll
    for (int q = 6; q < 10; q++) {
        const float* U = U0 + q*8;
        vr[q-6][0] = U[0]*cv[q] + U[2]*sv[q];  vi[q-6][0] = U[1]*cv[q] + U[3]*sv[q];
        vr[q-6][1] = U[4]*cv[q] + U[6]*sv[q];  vi[q-6][1] = U[5]*cv[q] + U[7]*sv[q];
    }
    float t67r[4], t67i[4], t89r[4], t89i[4];
    #pragma unroll
    for (int m = 0; m < 4; m++) {
        int b0 = m & 1, b1i = (m >> 1) & 1;
        t67r[m] = vr[0][b0]*vr[1][b1i] - vi[0][b0]*vi[1][b1i];
        t67i[m] = vr[0][b0]*vi[1][b1i] + vi[0][b0]*vr[1][b1i];
        t89r[m] = vr[2][b0]*vr[3][b1i] - vi[2][b0]*vi[3][b1i];
        t89i[m] = vr[2][b0]*vi[3][b1i] + vi[2][b0]*vr[3][b1i];
    }
    #pragma unroll
    for (int p = 0; p < 8; p++) {
        const int lo = p & 3, h0 = p >> 2, h1 = h0 + 2;
        float prr0 = t67r[lo]*t89r[h0] - t67i[lo]*t89i[h0];
        float pii0 = t67r[lo]*t89i[h0] + t67i[lo]*t89r[h0];
        float re0 = Lr*prr0 - Li*pii0, im0 = Lr*pii0 + Li*prr0;
        float prr1 = t67r[lo]*t89r[h1] - t67i[lo]*t89i[h1];
        float pii1 = t67r[lo]*t89i[h1] + t67i[lo]*t89r[h1];
        float re1 = Lr*prr1 - Li*pii1, im1 = Lr*pii1 + Li*prr1;
        pr[p] = __builtin_bit_cast(u32, __floats2half2_rn(re0, re1));
        pi[p] = __builtin_bit_cast(u32, __floats2half2_rn(im0, im1));
    }
}

template<int B>
__device__ __forceinline__ float st_signed(float v, int lane){
    float t = lx<B>(v);
    return ((lane >> B) & 1) ? (t - v) : (v - t);
}
template<int B>
__device__ __forceinline__ float st_plain(float v){
    if constexpr (B == 5) return sum32(v);
    else return v + lx<B>(v);
}
// full-signed butterfly (all 6 bits) -> value uniform across lanes
__device__ __forceinline__ float z_full(float v, int lane){
    v = st_signed<0>(v, lane);
    v = st_signed<1>(v, lane);
    v = st_signed<2>(v, lane);
    v = st_signed<3>(v, lane);
    v = st_signed<4>(v, lane);
    v = st_signed<5>(v, lane);
    return v;
}
// Walsh-Hadamard stage: lane m ends with W[m] = sum_l v_l (-1)^popcount(l&m)
template<int B>
__device__ __forceinline__ float wht_stage(float v, int lane){
    float t = lx<B>(v);
    return ((lane >> B) & 1) ? (t - v) : (v + t);
}
__device__ __forceinline__ float wht6(float v, int lane){
    v = wht_stage<0>(v, lane);
    v = wht_stage<1>(v, lane);
    v = wht_stage<2>(v, lane);
    v = wht_stage<3>(v, lane);
    v = wht_stage<4>(v, lane);
    v = wht_stage<5>(v, lane);
    return v;
}
__device__ __forceinline__ float rdlane(float v, int l){
    return i2f(__builtin_amdgcn_readlane(f2i(v), l));
}

// reg-side trees: |amp|^2 -> S (plain) and T[4] (signed on amp bits 0..3)
__device__ __forceinline__ void reduceRegs(const u32 (&pr)[8], const u32 (&pi)[8],
                                           float &S, float (&T)[4])
{
    float P[16];
    #pragma unroll
    for (int p = 0; p < 8; p++) {
        h2 a = b2h(pr[p]), b = b2h(pi[p]);
        float arl = __low2float(a),  ail = __low2float(b);
        float arh = __high2float(a), aih = __high2float(b);
        P[p]     = arl*arl + ail*ail;
        P[p + 8] = arh*arh + aih*aih;
    }
    float u[8], d[8];
    #pragma unroll
    for (int k = 0; k < 8; k++) { u[k] = P[2*k] + P[2*k+1]; d[k] = P[2*k] - P[2*k+1]; }
    S    = ((u[0]+u[1]) + (u[2]+u[3])) + ((u[4]+u[5]) + (u[6]+u[7]));
    T[0] = ((d[0]+d[1]) + (d[2]+d[3])) + ((d[4]+d[5]) + (d[6]+d[7]));
    float e0 = d[0]-d[1], e1 = d[2]-d[3], e2 = d[4]-d[5], e3 = d[6]-d[7];
    T[1] = (e0+e1) + (e2+e3);
    float f0 = e0-e1, f1 = e2-e3;
    T[2] = f0 + f1;
    T[3] = f0 - f1;
}

__global__ __launch_bounds__(256)
__attribute__((amdgpu_waves_per_eu(4, 8)))
void k_qsim(
        const float* __restrict__ x,
        const float* __restrict__ W1, const float* __restrict__ b1,
        const float* __restrict__ W2, const float* __restrict__ b2,
        const float* __restrict__ ws,
        const float* __restrict__ W3, const float* __restrict__ b3,
        const float* __restrict__ W4, const float* __restrict__ b4,
        float* __restrict__ out)
{
    const int lane = threadIdx.x & 63;
    int wid0 = (blockIdx.x * 256 + threadIdx.x) >> 6;
    const int wid = __builtin_amdgcn_readfirstlane(wid0);   // wave = sample pair

    // ---- front MLP for both samples (half-wave each) -----------------------
    float cA, sA;
    {
        const int j = lane & 31;
        const float* xr  = x + (2*wid + (lane >> 5)) * 64;  // uniform per half
        const float* w1r = W1 + j * 64;
        float a = b1[j];
        #pragma unroll
        for (int k = 0; k < 64; k += 4) {
            float4 xv = *reinterpret_cast<const float4*>(xr + k);
            float4 wv = *reinterpret_cast<const float4*>(w1r + k);
            a = fmaf(wv.x, xv.x, a);
            a = fmaf(wv.y, xv.y, a);
            a = fmaf(wv.z, xv.z, a);
            a = fmaf(wv.w, xv.w, a);
        }
        float h = fmaxf(a, 0.0f);

        float tsel = 0.0f;
        #pragma unroll
        for (int i = 0; i < 10; i++) {
            float t = W2[i*32 + j] * h;
            t = st_plain<4>(t);  t = st_plain<3>(t);  t = st_plain<2>(t);
            t = st_plain<1>(t);  t = st_plain<0>(t);  // sum within 32-lane half
            t += b2[i];
            if (j == i) tsel = t;     // lane i: A angle i; lane 32+i: B angle i
        }
        float ang = tanhf(tsel) * 1.5707963267948966f;   // (tanh*pi)*0.5
        __sincosf(ang, &sA, &cA);
    }

    u32 prA[8], piA[8], prB[8], piB[8];
    {
        float cv[10], sv[10];
        #pragma unroll
        for (int q = 0; q < 10; q++) {
            cv[q] = rdlane(cA, q);
            sv[q] = rdlane(sA, q);
        }
        init_stateH(prA, piA, cv, sv, ws, lane);
        #pragma unroll
        for (int q = 0; q < 10; q++) {
            cv[q] = rdlane(cA, 32 + q);
            sv[q] = rdlane(sA, 32 + q);
        }
        init_stateH(prB, piB, cv, sv, ws, lane);
    }

    const int  baddr = ((lane ^ (lane << 1)) & 63) << 2;
    const bool lpar  = __builtin_popcount(lane & 63) & 1;
    const u32* WH = reinterpret_cast<const u32*>(ws) + 480;

    // ---- layers, FULLY UNROLLED, phase-complementary A/B gate order --------
    #pragma unroll
    for (int l = 0; l < 5; ++l) {
        const u32* Ub = WH + l * 80;
        // A: DS phase (chain + lane gates)
        chainH(prA, baddr, lpar);
        chainH(piA, baddr, lpar);
        lane_gateH1<0>(prA, piA, Ub +  0, lane);
        lane_gateH1<1>(prA, piA, Ub +  8, lane);
        lane_gateH1<2>(prA, piA, Ub + 16, lane);
        lane_gateH1<3>(prA, piA, Ub + 24, lane);
        lane_gateH1<4>(prA, piA, Ub + 32, lane);
        lane_gateS5H1 (prA, piA, Ub + 40, lane);
        // B: DS chain — scheduler overlaps A's VALU reg gates below
        chainH(prB, baddr, lpar);
        chainH(piB, baddr, lpar);
        // A: VALU phase (reg gates, zero DS)
        reg_gateH1<1> (prA, piA, Ub + 48);
        reg_gateH1<2> (prA, piA, Ub + 56);
        reg_gateH1<4> (prA, piA, Ub + 64);
        q9_gateH1     (prA, piA, Ub + 72);
        // B: DS phase (lane gates)
        lane_gateH1<0>(prB, piB, Ub +  0, lane);
        lane_gateH1<1>(prB, piB, Ub +  8, lane);
        lane_gateH1<2>(prB, piB, Ub + 16, lane);
        lane_gateH1<3>(prB, piB, Ub + 24, lane);
        lane_gateH1<4>(prB, piB, Ub + 32, lane);
        lane_gateS5H1 (prB, piB, Ub + 40, lane);
        // B: VALU phase — overlaps next layer's chainA (loop fully unrolled)
        reg_gateH1<1> (prB, piB, Ub + 48);
        reg_gateH1<2> (prB, piB, Ub + 56);
        reg_gateH1<4> (prB, piB, Ub + 64);
        q9_gateH1     (prB, piB, Ub + 72);
    }

    // ---- readout: reg trees + one WHT per sample + 4 full-signed -----------
    float SA, TA[4], SB, TB[4];
    reduceRegs(prA, piA, SA, TA);
    reduceRegs(prB, piB, SB, TB);

    float WA = wht6(SA, lane);
    float WB = wht6(SB, lane);
    // z0..z5 = Walsh coefficients at prefix masks {1,3,7,15,31,63}
    float zA0 = rdlane(WA, 1),  zA1 = rdlane(WA, 3),  zA2 = rdlane(WA, 7);
    float zA3 = rdlane(WA, 15), zA4 = rdlane(WA, 31), zA5 = rdlane(WA, 63);
    float zB0 = rdlane(WB, 1),  zB1 = rdlane(WB, 3),  zB2 = rdlane(WB, 7);
    float zB3 = rdlane(WB, 15), zB4 = rdlane(WB, 31), zB5 = rdlane(WB, 63);
    // z6..z9: full-signed lane butterfly of T (uniform across lanes)
    float zA6 = z_full(TA[0], lane), zA7 = z_full(TA[1], lane);
    float zA8 = z_full(TA[2], lane), zA9 = z_full(TA[3], lane);
    float zB6 = z_full(TB[0], lane), zB7 = z_full(TB[1], lane);
    float zB8 = z_full(TB[2], lane), zB9 = z_full(TB[3], lane);

    // ---- tail MLP parallelized: lanes 0-15 sample A, 16-31 sample B --------
    {
        const bool isB = (lane >> 4) & 1;     // lanes 16-31 (and 48-63 junk)
        float z0 = isB ? zB0 : zA0,  z1 = isB ? zB1 : zA1;
        float z2 = isB ? zB2 : zA2,  z3 = isB ? zB3 : zA3;
        float z4 = isB ? zB4 : zA4,  z5 = isB ? zB5 : zA5;
        float z6 = isB ? zB6 : zA6,  z7 = isB ? zB7 : zA7;
        float z8 = isB ? zB8 : zA8,  z9 = isB ? zB9 : zA9;

        const int j = lane & 15;
        const float* w3r = W3 + j * 10;
        float a = b3[j];
        a = fmaf(w3r[0], z0, a);  a = fmaf(w3r[1], z1, a);
        a = fmaf(w3r[2], z2, a);  a = fmaf(w3r[3], z3, a);
        a = fmaf(w3r[4], z4, a);  a = fmaf(w3r[5], z5, a);
        a = fmaf(w3r[6], z6, a);  a = fmaf(w3r[7], z7, a);
        a = fmaf(w3r[8], z8, a);  a = fmaf(w3r[9], z9, a);
        a = fmaxf(a, 0.0f);
        float p0 = a * W4[j];
        float p1 = a * W4[16 + j];
        // reduce within 16-lane groups (bits 0..3)
        p0 = p0 + lx<0>(p0);  p1 = p1 + lx<0>(p1);
        p0 = p0 + lx<1>(p0);  p1 = p1 + lx<1>(p1);
        p0 = p0 + lx<2>(p0);  p1 = p1 + lx<2>(p1);
        p0 = p0 + lx<3>(p0);  p1 = p1 + lx<3>(p1);
        p0 += b4[0];
        p1 += b4[1];
        if ((lane & 0b101111) == 0) {         // lanes 0 (A) and 16 (B)
            reinterpret_cast<float2*>(out)[2*wid + (lane >> 4)] =
                make_float2(p0, p1);
        }
    }
}

extern "C" void kernel_launch(void* const* d_in, const int* in_sizes, int n_in,
                              void* d_out, int out_size, void* d_ws, size_t ws_size,
                              hipStream_t stream)
{
    (void)in_sizes; (void)n_in; (void)out_size; (void)ws_size;
    const float* x  = (const float*)d_in[0];
    const float* W1 = (const float*)d_in[1];
    const float* b1 = (const float*)d_in[2];
    const float* W2 = (const float*)d_in[3];
    const float* b2 = (const float*)d_in[4];
    const float* qp = (const float*)d_in[5];
    const float* W3 = (const float*)d_in[6];
    const float* b3 = (const float*)d_in[7];
    const float* W4 = (const float*)d_in[8];
    const float* b4 = (const float*)d_in[9];
    float* ws  = (float*)d_ws;
    float* out = (float*)d_out;

    k_prep<<<1, 64, 0, stream>>>(qp, ws);
    k_qsim<<<2048, 256, 0, stream>>>(x, W1, b1, W2, b2, ws, W3, b3, W4, b4, out);
}